// Round 1
// baseline (1255.682 us; speedup 1.0000x reference)
//
#include <hip/hip_runtime.h>
#include <stdint.h>

// ---------------------------------------------------------------------------
// TransformerBlock (masked-subnetwork block) for MI355X / gfx950.
// All internal matmuls in bf16 MFMA (16x16x32), LN folded into GEMM epilogues.
// Workspace usage ~241 MB.
// ---------------------------------------------------------------------------

#define SEQ 2048
#define DM 1024
#define NHEADS 16
#define DH 64
#define DMLP 4096
#define PN 35
#define TOTN 51
#define OUTN 52
#define LNEPS 1e-5f
#define L2E 1.44269504088896340736f

typedef __bf16 bf16x8 __attribute__((ext_vector_type(8)));
typedef float f32x4 __attribute__((ext_vector_type(4)));
typedef unsigned short u16x8 __attribute__((ext_vector_type(8)));

static __device__ __forceinline__ unsigned short f2bf(float f) {
    unsigned int u = __builtin_bit_cast(unsigned int, f);
    u += 0x7fffu + ((u >> 16) & 1u);
    return (unsigned short)(u >> 16);
}

static __device__ __forceinline__ float gelu_tanh(float x) {
    float u = 0.7978845608028654f * x * (1.f + 0.044715f * x * x);
    float e = exp2f(u * (2.f * L2E));          // e^{2u}
    float th = 1.f - 2.f / (e + 1.f);          // tanh(u)
    return 0.5f * x * (1.f + th);
}

// ---------------------------------------------------------------------------
// prep kernels
// ---------------------------------------------------------------------------
__global__ void prep_masks(const float* __restrict__ mq, const float* __restrict__ mk,
                           const float* __restrict__ mv, const float* __restrict__ mmlp,
                           const float* __restrict__ bQ, const float* __restrict__ bK,
                           const float* __restrict__ bV,
                           float* __restrict__ maskP2, float* __restrict__ mlpmaskf,
                           float* __restrict__ biasQKV) {
    int t = threadIdx.x;
    if (t < 48) {
        int ty = t >> 4, h = t & 15;
        const float* src = (ty == 0) ? mq : (ty == 1 ? mk : mv);
        for (int n = 0; n < PN; ++n) maskP2[t * 64 + n] = (src[n * NHEADS + h] > 0.f) ? 1.f : 0.f;
        for (int n = PN; n < 64; ++n) maskP2[t * 64 + n] = 0.f;
        const float* bsrc = (ty == 0) ? bQ : (ty == 1 ? bK : bV);
        for (int d = 0; d < DH; ++d) biasQKV[t * 64 + d] = bsrc[h * DH + d];
    }
    if (t < TOTN) mlpmaskf[t] = (mmlp[t] > 0.f) ? 1.f : 0.f;
}

__global__ void prep_rotary(float* __restrict__ rot) {
    int id = blockIdx.x * blockDim.x + threadIdx.x;   // 2048*32
    int s = id >> 5, j = id & 31;
    float freq = powf(10000.f, (float)j * (1.f / 32.f));
    float ang = (float)s / freq;
    rot[s * 64 + j] = sinf(ang);
    rot[s * 64 + 32 + j] = cosf(ang);
}

// colsum over K of W (KxN row-major); blockIdx.y selects matrix (stride K*N)
__global__ void colsum_k(const float* __restrict__ W, float* __restrict__ out, int K, int N) {
    int h = blockIdx.y;
    const float* Wb = W + (size_t)h * K * N;
    int col = blockIdx.x * 64 + (threadIdx.x & 63);
    int kg = threadIdx.x >> 6;
    int kPer = K >> 2;
    float s = 0.f;
    for (int kk = 0; kk < kPer; ++kk) s += Wb[(size_t)(kg * kPer + kk) * N + col];
    __shared__ float part[4][64];
    part[kg][threadIdx.x & 63] = s;
    __syncthreads();
    if (threadIdx.x < 64)
        out[h * N + blockIdx.x * 64 + threadIdx.x] =
            part[0][threadIdx.x] + part[1][threadIdx.x] + part[2][threadIdx.x] + part[3][threadIdx.x];
}

// ---------------------------------------------------------------------------
// K1: per sequence position s: copy resid_pre -> out rows 0..34, compute the
// 48 masked sums (q/k/v x 16 heads) raw in bf16, and their LN stats.
// 512 threads, each owns 2 of the 1024 model dims.
// ---------------------------------------------------------------------------
__launch_bounds__(512, 1)
__global__ void k1_masked_norm(const float* __restrict__ resid,
                               const float* __restrict__ maskP2,
                               float* __restrict__ outp,
                               unsigned short* __restrict__ nrm,
                               float* __restrict__ stats) {
    int s = blockIdx.x;
    int tid = threadIdx.x;
    int lane = tid & 63, w = tid >> 6;
    const float2* rp = (const float2*)(resid + (size_t)s * PN * DM);
    float2* outv = (float2*)(outp + (size_t)s * OUTN * DM);
    float2 r[PN];
#pragma unroll
    for (int n = 0; n < PN; ++n) {
        float2 v = rp[n * (DM / 2) + tid];
        r[n] = v;
        outv[n * (DM / 2) + tid] = v;
    }
    __shared__ float wpart[8][48][2];
#pragma unroll 1
    for (int th = 0; th < 48; ++th) {
        float sx = 0.f, sy = 0.f;
#pragma unroll
        for (int n = 0; n < PN; ++n) {
            float mk = maskP2[th * 64 + n];   // uniform -> s_load
            sx += r[n].x * mk;
            sy += r[n].y * mk;
        }
        unsigned int pk = (unsigned int)f2bf(sx) | ((unsigned int)f2bf(sy) << 16);
        ((unsigned int*)nrm)[((size_t)th * SEQ + s) * (DM / 2) + tid] = pk;
        float p1 = sx + sy, p2 = sx * sx + sy * sy;
#pragma unroll
        for (int d = 1; d < 64; d <<= 1) {
            p1 += __shfl_xor(p1, d);
            p2 += __shfl_xor(p2, d);
        }
        if (lane == 0) { wpart[w][th][0] = p1; wpart[w][th][1] = p2; }
    }
    __syncthreads();
    if (tid < 48) {
        float S1 = 0.f, S2 = 0.f;
        for (int ww = 0; ww < 8; ++ww) { S1 += wpart[ww][tid][0]; S2 += wpart[ww][tid][1]; }
        float mean = S1 * (1.f / DM);
        float var = S2 * (1.f / DM) - mean * mean;
        float* st = stats + ((size_t)tid * SEQ + s) * 2;
        st[0] = mean;
        st[1] = rsqrtf(var + LNEPS);
    }
}

// ---------------------------------------------------------------------------
// K4: masked sum over 51 residual nodes (read from d_out rows 0..50) + stats.
// ---------------------------------------------------------------------------
__launch_bounds__(256, 2)
__global__ void k4_mlp_mask(const float* __restrict__ outp, const float* __restrict__ mlpmaskf,
                            unsigned short* __restrict__ mid, float* __restrict__ stats) {
    int s = blockIdx.x, tid = threadIdx.x;
    int lane = tid & 63, w = tid >> 6;
    const float4* base = (const float4*)(outp + (size_t)s * OUTN * DM);
    float4 acc = make_float4(0.f, 0.f, 0.f, 0.f);
    for (int n = 0; n < TOTN; ++n) {
        float mk = mlpmaskf[n];               // uniform
        if (mk != 0.f) {
            float4 v = base[n * (DM / 4) + tid];
            acc.x += v.x; acc.y += v.y; acc.z += v.z; acc.w += v.w;
        }
    }
    unsigned int lo = (unsigned int)f2bf(acc.x) | ((unsigned int)f2bf(acc.y) << 16);
    unsigned int hi = (unsigned int)f2bf(acc.z) | ((unsigned int)f2bf(acc.w) << 16);
    ((uint2*)mid)[(size_t)s * (DM / 4) + tid] = make_uint2(lo, hi);
    float p1 = acc.x + acc.y + acc.z + acc.w;
    float p2 = acc.x * acc.x + acc.y * acc.y + acc.z * acc.z + acc.w * acc.w;
#pragma unroll
    for (int d = 1; d < 64; d <<= 1) { p1 += __shfl_xor(p1, d); p2 += __shfl_xor(p2, d); }
    __shared__ float wp[4][2];
    if (lane == 0) { wp[w][0] = p1; wp[w][1] = p2; }
    __syncthreads();
    if (tid == 0) {
        float S1 = wp[0][0] + wp[1][0] + wp[2][0] + wp[3][0];
        float S2 = wp[0][1] + wp[1][1] + wp[2][1] + wp[3][1];
        float mean = S1 * (1.f / DM);
        float var = S2 * (1.f / DM) - mean * mean;
        stats[s * 2] = mean;
        stats[s * 2 + 1] = rsqrtf(var + LNEPS);
    }
}

// ---------------------------------------------------------------------------
// Generic bf16 MFMA GEMM.  A: MxK bf16 row-major.  B: KxN f32 row-major
// (converted to bf16 during LDS staging, stored transposed).
// EPI 0: f32 out + bias*scale   (attn-out into d_out, MLP2 into d_out)
// EPI 1: LN-affine + bias (+rotary, q*0.125) -> bf16   (QKV projection)
// EPI 2: LN-affine + bias + gelu -> bf16               (MLP1)
// ---------------------------------------------------------------------------
template <int MF, int NF, int WGM, int WGN, int EPI>
__launch_bounds__(256, 2)
__global__ void gemm_k(const unsigned short* __restrict__ A, size_t aStrideZ, int lda,
                       const float* __restrict__ B0, const float* __restrict__ B1,
                       const float* __restrict__ B2, size_t bStrideZ, int ldb, int bSel,
                       float* __restrict__ Cf, unsigned short* __restrict__ Cb,
                       size_t cStrideZ, int ldc,
                       const float* __restrict__ stats, size_t statsStrideZ,
                       const float* __restrict__ colW, size_t colwStrideZ,
                       const float* __restrict__ bias, size_t biasStrideZ, float biasScale,
                       const float* __restrict__ rot, int K) {
    constexpr int BM = WGM * 16 * MF;
    constexpr int BN = WGN * 16 * NF;
    static_assert(BM * BN / (16 * 16) == 4 * MF * NF, "wave layout");
    __shared__ unsigned short As[BM][72];   // 144B row stride: 16B aligned, 2-way conflicts
    __shared__ unsigned short Bt[BN][72];
    const int tid = threadIdx.x;
    const int lane = tid & 63;
    const int w = tid >> 6;
    const int wm = w % WGM, wn = w / WGM;
    const int z = blockIdx.z;
    const int m0 = blockIdx.x * BM;
    const int n0 = blockIdx.y * BN;

    const unsigned short* Ab = A + (size_t)z * aStrideZ;
    const float* Bb;
    if (bSel == 0) {
        Bb = B0 + (size_t)z * bStrideZ;
    } else {
        int t = z >> 4;
        Bb = ((t == 0) ? B0 : (t == 1 ? B1 : B2)) + (size_t)(z & 15) * bStrideZ;
    }

    f32x4 acc[MF][NF];
#pragma unroll
    for (int mf = 0; mf < MF; ++mf)
#pragma unroll
        for (int nf = 0; nf < NF; ++nf) acc[mf][nf] = 0.f;

    constexpr int AIT = (BM * 64) / (256 * 8);
    constexpr int BG = 256 / BN;
    constexpr int KPER = 64 / BG;
    const int bc = tid % BN, bkg = tid / BN;

    for (int k0 = 0; k0 < K; k0 += 64) {
        __syncthreads();
#pragma unroll
        for (int i = 0; i < AIT; ++i) {
            int idx = tid + i * 256;
            int row = idx >> 3, c8 = (idx & 7) * 8;
            *(u16x8*)&As[row][c8] = *(const u16x8*)(Ab + (size_t)(m0 + row) * lda + k0 + c8);
        }
#pragma unroll
        for (int kk = 0; kk < KPER; kk += 2) {
            int k = bkg * KPER + kk;
            float f0 = Bb[(size_t)(k0 + k) * ldb + n0 + bc];
            float f1 = Bb[(size_t)(k0 + k + 1) * ldb + n0 + bc];
            *(unsigned int*)&Bt[bc][k] = (unsigned int)f2bf(f0) | ((unsigned int)f2bf(f1) << 16);
        }
        __syncthreads();
#pragma unroll
        for (int ks = 0; ks < 2; ++ks) {
            bf16x8 a[MF], b[NF];
#pragma unroll
            for (int mf = 0; mf < MF; ++mf)
                a[mf] = *(const bf16x8*)&As[wm * (16 * MF) + mf * 16 + (lane & 15)][ks * 32 + (lane >> 4) * 8];
#pragma unroll
            for (int nf = 0; nf < NF; ++nf)
                b[nf] = *(const bf16x8*)&Bt[wn * (16 * NF) + nf * 16 + (lane & 15)][ks * 32 + (lane >> 4) * 8];
#pragma unroll
            for (int mf = 0; mf < MF; ++mf)
#pragma unroll
                for (int nf = 0; nf < NF; ++nf)
                    acc[mf][nf] = __builtin_amdgcn_mfma_f32_16x16x32_bf16(a[mf], b[nf], acc[mf][nf], 0, 0, 0);
        }
    }

    const int cl = lane & 15, rq = lane >> 4;

    if constexpr (EPI == 0) {
        float* Cz = Cf + (size_t)z * cStrideZ;
        const float* bz = bias + (size_t)z * biasStrideZ;
#pragma unroll
        for (int mf = 0; mf < MF; ++mf)
#pragma unroll
            for (int nf = 0; nf < NF; ++nf) {
                int col = n0 + wn * (16 * NF) + nf * 16 + cl;
                float bv = bz[col] * biasScale;
#pragma unroll
                for (int rr = 0; rr < 4; ++rr) {
                    int row = m0 + wm * (16 * MF) + mf * 16 + rq * 4 + rr;
                    Cz[(size_t)row * ldc + col] = acc[mf][nf][rr] + bv;
                }
            }
    } else if constexpr (EPI == 1) {
        unsigned short* Cz = Cb + (size_t)z * cStrideZ;
        const int t = z >> 4;                      // 0=q 1=k 2=v
        const float qs = (t == 0) ? 0.125f : 1.f;  // fold 1/sqrt(D_HEAD)
        float vals[MF][NF][4];
        float meanv[MF][4], invv[MF][4];
#pragma unroll
        for (int mf = 0; mf < MF; ++mf)
#pragma unroll
            for (int rr = 0; rr < 4; ++rr) {
                int row = m0 + wm * (16 * MF) + mf * 16 + rq * 4 + rr;
                const float* st = stats + ((size_t)z * statsStrideZ + row) * 2;
                meanv[mf][rr] = st[0];
                invv[mf][rr] = st[1];
            }
#pragma unroll
        for (int nf = 0; nf < NF; ++nf) {
            int col = n0 + wn * (16 * NF) + nf * 16 + cl;
            float cw = colW[(size_t)z * colwStrideZ + col];
            float bv = bias[(size_t)z * biasStrideZ + col];
#pragma unroll
            for (int mf = 0; mf < MF; ++mf)
#pragma unroll
                for (int rr = 0; rr < 4; ++rr)
                    vals[mf][nf][rr] = (acc[mf][nf][rr] - meanv[mf][rr] * cw) * invv[mf][rr] + bv;
        }
        if (t < 2) {   // rotary on q,k  (requires WGN==1, n0==0, NF==4 -> d pairs (nf, nf+2))
#pragma unroll
            for (int nf = 0; nf < NF / 2; ++nf) {
                int j = nf * 16 + cl;   // d_lo in [0,32)
#pragma unroll
                for (int mf = 0; mf < MF; ++mf)
#pragma unroll
                    for (int rr = 0; rr < 4; ++rr) {
                        int row = m0 + wm * (16 * MF) + mf * 16 + rq * 4 + rr;
                        float sn = rot[row * 64 + j];
                        float cs = rot[row * 64 + 32 + j];
                        float lo = vals[mf][nf][rr], hi = vals[mf][nf + 2][rr];
                        vals[mf][nf][rr] = lo * cs - hi * sn;
                        vals[mf][nf + 2][rr] = hi * cs + lo * sn;
                    }
            }
        }
#pragma unroll
        for (int mf = 0; mf < MF; ++mf)
#pragma unroll
            for (int nf = 0; nf < NF; ++nf) {
                int col = n0 + wn * (16 * NF) + nf * 16 + cl;
#pragma unroll
                for (int rr = 0; rr < 4; ++rr) {
                    int row = m0 + wm * (16 * MF) + mf * 16 + rq * 4 + rr;
                    Cz[(size_t)row * ldc + col] = f2bf(vals[mf][nf][rr] * qs);
                }
            }
    } else {  // EPI == 2 : LN-affine + bias + gelu -> bf16
        unsigned short* Cz = Cb;
#pragma unroll
        for (int mf = 0; mf < MF; ++mf)
#pragma unroll
            for (int rr = 0; rr < 4; ++rr) {
                int row = m0 + wm * (16 * MF) + mf * 16 + rq * 4 + rr;
                const float* st = stats + (size_t)row * 2;
                float mean = st[0], inv = st[1];
#pragma unroll
                for (int nf = 0; nf < NF; ++nf) {
                    int col = n0 + wn * (16 * NF) + nf * 16 + cl;
                    float x = (acc[mf][nf][rr] - mean * colW[col]) * inv + bias[col];
                    Cz[(size_t)row * ldc + col] = f2bf(gelu_tanh(x));
                }
            }
    }
}

// ---------------------------------------------------------------------------
// Flash attention: 16 heads, S=2048, D=64, causal.  q already scaled by 1/8.
// Block = 4 waves, 64 q-rows (16/wave), KV tiles of 64.
// ---------------------------------------------------------------------------
__launch_bounds__(256, 2)
__global__ void flash_k(const unsigned short* __restrict__ qkv,
                        unsigned short* __restrict__ zbuf) {
    const int qi = blockIdx.x, h = blockIdx.y;
    const int tid = threadIdx.x, lane = tid & 63, w = tid >> 6;
    const int cl = lane & 15, rq = lane >> 4;
    const unsigned short* qb = qkv;
    const unsigned short* kb = qkv + (size_t)NHEADS * SEQ * DH;
    const unsigned short* vb = kb + (size_t)NHEADS * SEQ * DH;
    const int q0 = qi * 64;

    __shared__ unsigned short Ks[64][72];
    __shared__ unsigned short Vt[64][72];
    __shared__ unsigned short Ps[64][72];

    bf16x8 aq[2];
    {
        int qrow = q0 + w * 16 + cl;
        const unsigned short* qp = qb + ((size_t)h * SEQ + qrow) * DH + rq * 8;
        aq[0] = *(const bf16x8*)(qp);
        aq[1] = *(const bf16x8*)(qp + 32);
    }
    float m_run[4] = {-3e38f, -3e38f, -3e38f, -3e38f};
    float l_run[4] = {0.f, 0.f, 0.f, 0.f};
    f32x4 accz[4];
#pragma unroll
    for (int nf = 0; nf < 4; ++nf) accz[nf] = 0.f;

    for (int j = 0; j <= qi; ++j) {
        __syncthreads();
        const unsigned short* kt = kb + ((size_t)h * SEQ + j * 64) * DH;
        const unsigned short* vt = vb + ((size_t)h * SEQ + j * 64) * DH;
#pragma unroll
        for (int i = 0; i < 2; ++i) {
            int idx = tid + i * 256;
            int row = idx >> 3, c8 = (idx & 7) * 8;
            *(u16x8*)&Ks[row][c8] = *(const u16x8*)(kt + (size_t)row * DH + c8);
            u16x8 v = *(const u16x8*)(vt + (size_t)row * DH + c8);
#pragma unroll
            for (int e = 0; e < 8; ++e) Vt[c8 + e][row] = v[e];
        }
        __syncthreads();

        f32x4 sfr[4];
#pragma unroll
        for (int nf = 0; nf < 4; ++nf) sfr[nf] = 0.f;
#pragma unroll
        for (int df = 0; df < 2; ++df)
#pragma unroll
            for (int nf = 0; nf < 4; ++nf) {
                bf16x8 b = *(const bf16x8*)&Ks[nf * 16 + cl][df * 32 + rq * 8];
                sfr[nf] = __builtin_amdgcn_mfma_f32_16x16x32_bf16(aq[df], b, sfr[nf], 0, 0, 0);
            }
        if (j == qi) {
#pragma unroll
            for (int nf = 0; nf < 4; ++nf)
#pragma unroll
                for (int rr = 0; rr < 4; ++rr) {
                    int qg = q0 + w * 16 + rq * 4 + rr;
                    int kg = j * 64 + nf * 16 + cl;
                    if (kg > qg) sfr[nf][rr] = -1e5f;
                }
        }
        float mnew[4], corr[4], psum[4];
#pragma unroll
        for (int rr = 0; rr < 4; ++rr) {
            float t0 = fmaxf(fmaxf(sfr[0][rr], sfr[1][rr]), fmaxf(sfr[2][rr], sfr[3][rr]));
            t0 = fmaxf(t0, __shfl_xor(t0, 1));
            t0 = fmaxf(t0, __shfl_xor(t0, 2));
            t0 = fmaxf(t0, __shfl_xor(t0, 4));
            t0 = fmaxf(t0, __shfl_xor(t0, 8));
            mnew[rr] = fmaxf(m_run[rr], t0);
            corr[rr] = exp2f((m_run[rr] - mnew[rr]) * L2E);
            psum[rr] = 0.f;
        }
#pragma unroll
        for (int nf = 0; nf < 4; ++nf)
#pragma unroll
            for (int rr = 0; rr < 4; ++rr) {
                float p = exp2f((sfr[nf][rr] - mnew[rr]) * L2E);
                sfr[nf][rr] = p;
                psum[rr] += p;
            }
#pragma unroll
        for (int rr = 0; rr < 4; ++rr) {
            float ps = psum[rr];
            ps += __shfl_xor(ps, 1);
            ps += __shfl_xor(ps, 2);
            ps += __shfl_xor(ps, 4);
            ps += __shfl_xor(ps, 8);
            l_run[rr] = l_run[rr] * corr[rr] + ps;
            m_run[rr] = mnew[rr];
        }
#pragma unroll
        for (int nf = 0; nf < 4; ++nf)
#pragma unroll
            for (int rr = 0; rr < 4; ++rr) accz[nf][rr] *= corr[rr];

        // P -> LDS (wave-private 16 rows), then consume as MFMA A operand
#pragma unroll
        for (int nf = 0; nf < 4; ++nf)
#pragma unroll
            for (int rr = 0; rr < 4; ++rr)
                Ps[w * 16 + rq * 4 + rr][nf * 16 + cl] = f2bf(sfr[nf][rr]);
#pragma unroll
        for (int ks = 0; ks < 2; ++ks) {
            bf16x8 ap = *(const bf16x8*)&Ps[w * 16 + cl][ks * 32 + rq * 8];
#pragma unroll
            for (int nf = 0; nf < 4; ++nf) {
                bf16x8 bv = *(const bf16x8*)&Vt[nf * 16 + cl][ks * 32 + rq * 8];
                accz[nf] = __builtin_amdgcn_mfma_f32_16x16x32_bf16(ap, bv, accz[nf], 0, 0, 0);
            }
        }
    }
#pragma unroll
    for (int nf = 0; nf < 4; ++nf)
#pragma unroll
        for (int rr = 0; rr < 4; ++rr) {
            int qg = q0 + w * 16 + rq * 4 + rr;
            zbuf[((size_t)h * SEQ + qg) * DH + nf * 16 + cl] = f2bf(accz[nf][rr] / l_run[rr]);
        }
}

// ---------------------------------------------------------------------------
extern "C" void kernel_launch(void* const* d_in, const int* in_sizes, int n_in,
                              void* d_out, int out_size, void* d_ws, size_t ws_size,
                              hipStream_t stream) {
    const float* resid = (const float*)d_in[0];
    const float* W_Q = (const float*)d_in[1];
    const float* b_Q = (const float*)d_in[2];
    const float* W_K = (const float*)d_in[3];
    const float* b_K = (const float*)d_in[4];
    const float* W_V = (const float*)d_in[5];
    const float* b_V = (const float*)d_in[6];
    const float* W_O = (const float*)d_in[7];
    const float* b_O = (const float*)d_in[8];
    const float* mql = (const float*)d_in[9];
    const float* mkl = (const float*)d_in[10];
    const float* mvl = (const float*)d_in[11];
    const float* mml = (const float*)d_in[12];
    const float* W_in = (const float*)d_in[13];
    const float* b_in = (const float*)d_in[14];
    const float* W_out = (const float*)d_in[15];
    const float* b_out = (const float*)d_in[16];
    float* out = (float*)d_out;
    (void)in_sizes; (void)n_in; (void)out_size; (void)ws_size;

    char* ws = (char*)d_ws;
    size_t off = 0;
    auto carve = [&](size_t bytes) -> void* {
        void* p = ws + off;
        off += (bytes + 255) & ~(size_t)255;
        return p;
    };
    unsigned short* nrm = (unsigned short*)carve((size_t)48 * SEQ * DM * 2);  // 192 MB raw masked sums
    float* statsQ = (float*)carve((size_t)48 * SEQ * 2 * 4);
    unsigned short* qkv = (unsigned short*)carve((size_t)48 * SEQ * DH * 2);
    unsigned short* zbuf = (unsigned short*)carve((size_t)NHEADS * SEQ * DH * 2);
    unsigned short* mid = (unsigned short*)carve((size_t)SEQ * DM * 2);
    float* statsM = (float*)carve((size_t)SEQ * 2 * 4);
    unsigned short* act = (unsigned short*)carve((size_t)SEQ * DMLP * 2);
    float* rot = (float*)carve((size_t)SEQ * 64 * 4);
    float* colWqkv = (float*)carve((size_t)48 * 64 * 4);
    float* colWin = (float*)carve((size_t)DMLP * 4);
    float* maskP2 = (float*)carve((size_t)48 * 64 * 4);
    float* mlpmaskf = (float*)carve((size_t)64 * 4);
    float* biasQKV = (float*)carve((size_t)48 * 64 * 4);
    // total ~241 MB of d_ws

    prep_masks<<<1, 64, 0, stream>>>(mql, mkl, mvl, mml, b_Q, b_K, b_V, maskP2, mlpmaskf, biasQKV);
    prep_rotary<<<256, 256, 0, stream>>>(rot);
    colsum_k<<<dim3(1, 16), 256, 0, stream>>>(W_Q, colWqkv, 1024, 64);
    colsum_k<<<dim3(1, 16), 256, 0, stream>>>(W_K, colWqkv + 1024, 1024, 64);
    colsum_k<<<dim3(1, 16), 256, 0, stream>>>(W_V, colWqkv + 2048, 1024, 64);
    colsum_k<<<dim3(64, 1), 256, 0, stream>>>(W_in, colWin, 1024, DMLP);

    k1_masked_norm<<<SEQ, 512, 0, stream>>>(resid, maskP2, out, nrm, statsQ);

    // QKV projection: 48 GEMMs (2048x1024x64), LN fold + bias + rotary + q*0.125
    gemm_k<2, 4, 4, 1, 1><<<dim3(16, 1, 48), 256, 0, stream>>>(
        nrm, (size_t)SEQ * DM, DM,
        W_Q, W_K, W_V, (size_t)DM * DH, DH, 1,
        nullptr, qkv, (size_t)SEQ * DH, DH,
        statsQ, SEQ,
        colWqkv, 64,
        biasQKV, 64, 1.f,
        rot, DM);

    flash_k<<<dim3(32, 16), 256, 0, stream>>>(qkv, zbuf);

    // attn_out per head: (2048x64)@(64x1024) + b_O/16 -> d_out rows 35..50
    gemm_k<4, 4, 2, 2, 0><<<dim3(16, 8, 16), 256, 0, stream>>>(
        zbuf, (size_t)SEQ * DH, DH,
        W_O, nullptr, nullptr, (size_t)DH * DM, DM, 0,
        out + 35 * DM, nullptr, (size_t)DM, OUTN * DM,
        nullptr, 0, nullptr, 0,
        b_O, 0, 1.f / 16.f,
        nullptr, DH);

    k4_mlp_mask<<<SEQ, 256, 0, stream>>>(out, mlpmaskf, mid, statsM);

    // MLP1: (2048x1024)@(1024x4096), LN fold + b_in + gelu -> act
    gemm_k<4, 4, 2, 2, 2><<<dim3(16, 32, 1), 256, 0, stream>>>(
        mid, 0, DM,
        W_in, nullptr, nullptr, 0, DMLP, 0,
        nullptr, act, 0, DMLP,
        statsM, 0,
        colWin, 0,
        b_in, 0, 1.f,
        nullptr, DM);

    // MLP2: (2048x4096)@(4096x1024) + b_out -> d_out row 51
    gemm_k<4, 4, 2, 2, 0><<<dim3(16, 8, 1), 256, 0, stream>>>(
        act, 0, DMLP,
        W_out, nullptr, nullptr, 0, DM, 0,
        out + 51 * DM, nullptr, 0, OUTN * DM,
        nullptr, 0, nullptr, 0,
        b_out, 0, 1.f,
        nullptr, DMLP);
}

// Round 2
// 978.142 us; speedup vs baseline: 1.2837x; 1.2837x over previous
//
#include <hip/hip_runtime.h>
#include <stdint.h>

// ---------------------------------------------------------------------------
// TransformerBlock (masked-subnetwork block) for MI355X / gfx950.
// Round 2: all GEMMs rebuilt on the m97 gemm_bt structure:
//   weights pre-transposed/converted to bf16 NxK, global_load_lds(16B)
//   staging into linear LDS, BK=64, 2-barrier loop, ds_read_b128 fragments.
// ---------------------------------------------------------------------------

#define SEQ 2048
#define DM 1024
#define NHEADS 16
#define DH 64
#define DMLP 4096
#define PN 35
#define TOTN 51
#define OUTN 52
#define LNEPS 1e-5f
#define L2E 1.44269504088896340736f

typedef __bf16 bf16x8 __attribute__((ext_vector_type(8)));
typedef float f32x4 __attribute__((ext_vector_type(4)));
typedef unsigned short u16x8 __attribute__((ext_vector_type(8)));

static __device__ __forceinline__ unsigned short f2bf(float f) {
    unsigned int u = __builtin_bit_cast(unsigned int, f);
    u += 0x7fffu + ((u >> 16) & 1u);
    return (unsigned short)(u >> 16);
}

static __device__ __forceinline__ float gelu_tanh(float x) {
    float u = 0.7978845608028654f * x * (1.f + 0.044715f * x * x);
    float e = exp2f(u * (2.f * L2E));          // e^{2u}
    float th = 1.f - 2.f / (e + 1.f);          // tanh(u)
    return 0.5f * x * (1.f + th);
}

// async global->LDS, 16B per lane; lds dest must be wave-uniform base.
static __device__ __forceinline__ void gload_lds16(const void* g, void* l) {
    __builtin_amdgcn_global_load_lds(
        (const __attribute__((address_space(1))) unsigned int*)g,
        (__attribute__((address_space(3))) unsigned int*)l, 16, 0, 0);
}

// ---------------------------------------------------------------------------
// prep kernels
// ---------------------------------------------------------------------------
__global__ void prep_masks(const float* __restrict__ mq, const float* __restrict__ mk,
                           const float* __restrict__ mv, const float* __restrict__ mmlp,
                           const float* __restrict__ bQ, const float* __restrict__ bK,
                           const float* __restrict__ bV,
                           float* __restrict__ maskP2, float* __restrict__ mlpmaskf,
                           float* __restrict__ biasQKV) {
    int t = threadIdx.x;
    if (t < 48) {
        int ty = t >> 4, h = t & 15;
        const float* src = (ty == 0) ? mq : (ty == 1 ? mk : mv);
        for (int n = 0; n < PN; ++n) maskP2[t * 64 + n] = (src[n * NHEADS + h] > 0.f) ? 1.f : 0.f;
        for (int n = PN; n < 64; ++n) maskP2[t * 64 + n] = 0.f;
        const float* bsrc = (ty == 0) ? bQ : (ty == 1 ? bK : bV);
        for (int d = 0; d < DH; ++d) biasQKV[t * 64 + d] = bsrc[h * DH + d];
    }
    if (t < TOTN) mlpmaskf[t] = (mmlp[t] > 0.f) ? 1.f : 0.f;
    if (t >= TOTN && t < 64) mlpmaskf[t] = 0.f;
}

__global__ void prep_rotary(float* __restrict__ rot) {
    int id = blockIdx.x * blockDim.x + threadIdx.x;   // 2048*32
    int s = id >> 5, j = id & 31;
    float freq = powf(10000.f, (float)j * (1.f / 32.f));
    float ang = (float)s / freq;
    rot[s * 64 + j] = sinf(ang);
    rot[s * 64 + 32 + j] = cosf(ang);
}

// colsum over K of W (KxN row-major); blockIdx.y selects matrix (stride K*N)
__global__ void colsum_k(const float* __restrict__ W, float* __restrict__ out, int K, int N) {
    int h = blockIdx.y;
    const float* Wb = W + (size_t)h * K * N;
    int col = blockIdx.x * 64 + (threadIdx.x & 63);
    int kg = threadIdx.x >> 6;
    int kPer = K >> 2;
    float s = 0.f;
    for (int kk = 0; kk < kPer; ++kk) s += Wb[(size_t)(kg * kPer + kk) * N + col];
    __shared__ float part[4][64];
    part[kg][threadIdx.x & 63] = s;
    __syncthreads();
    if (threadIdx.x < 64)
        out[h * N + blockIdx.x * 64 + threadIdx.x] =
            part[0][threadIdx.x] + part[1][threadIdx.x] + part[2][threadIdx.x] + part[3][threadIdx.x];
}

// transpose+convert: in f32 KxN row-major -> out bf16 NxK row-major (per z)
__global__ void wtrans(const float* __restrict__ in, unsigned short* __restrict__ out,
                       int K, int N, size_t inZ, size_t outZ) {
    int z = blockIdx.z;
    const float* ib = in + (size_t)z * inZ;
    unsigned short* ob = out + (size_t)z * outZ;
    __shared__ float t[32][33];
    int n0 = blockIdx.x * 32, k0 = blockIdx.y * 32;
    int tx = threadIdx.x & 31, ty = threadIdx.x >> 5;   // 32x8
#pragma unroll
    for (int r = 0; r < 4; ++r) {
        int k = ty + r * 8;
        t[k][tx] = ib[(size_t)(k0 + k) * N + n0 + tx];
    }
    __syncthreads();
#pragma unroll
    for (int r = 0; r < 4; ++r) {
        int n = ty + r * 8;
        ob[(size_t)(n0 + n) * K + k0 + tx] = f2bf(t[tx][n]);
    }
}

// ---------------------------------------------------------------------------
// K1: per sequence position s: copy resid_pre -> out rows 0..34, compute the
// 48 masked sums (q/k/v x 16 heads) raw in bf16 + their LN stats, and the
// masked-prev-node partial sum for the MLP path (f32).
// ---------------------------------------------------------------------------
__launch_bounds__(512, 1)
__global__ void k1_masked_norm(const float* __restrict__ resid,
                               const float* __restrict__ maskP2,
                               const float* __restrict__ mlpmaskf,
                               float* __restrict__ outp,
                               unsigned short* __restrict__ nrm,
                               float* __restrict__ stats,
                               float* __restrict__ prevpart) {
    int s = blockIdx.x;
    int tid = threadIdx.x;
    int lane = tid & 63, w = tid >> 6;
    const float2* rp = (const float2*)(resid + (size_t)s * PN * DM);
    float2* outv = (float2*)(outp + (size_t)s * OUTN * DM);
    float2 r[PN];
#pragma unroll
    for (int n = 0; n < PN; ++n) {
        float2 v = rp[n * (DM / 2) + tid];
        r[n] = v;
        outv[n * (DM / 2) + tid] = v;
    }
    __shared__ float wpart[8][48][2];
#pragma unroll 1
    for (int th = 0; th < 48; ++th) {
        float sx = 0.f, sy = 0.f;
#pragma unroll
        for (int n = 0; n < PN; ++n) {
            float mk = maskP2[th * 64 + n];   // uniform -> s_load
            sx += r[n].x * mk;
            sy += r[n].y * mk;
        }
        unsigned int pk = (unsigned int)f2bf(sx) | ((unsigned int)f2bf(sy) << 16);
        ((unsigned int*)nrm)[((size_t)th * SEQ + s) * (DM / 2) + tid] = pk;
        float p1 = sx + sy, p2 = sx * sx + sy * sy;
#pragma unroll
        for (int d = 1; d < 64; d <<= 1) {
            p1 += __shfl_xor(p1, d);
            p2 += __shfl_xor(p2, d);
        }
        if (lane == 0) { wpart[w][th][0] = p1; wpart[w][th][1] = p2; }
    }
    // masked-prev-node partial for MLP residual (f32)
    {
        float px = 0.f, py = 0.f;
#pragma unroll
        for (int n = 0; n < PN; ++n) {
            float mk = mlpmaskf[n];
            px += r[n].x * mk;
            py += r[n].y * mk;
        }
        ((float2*)prevpart)[(size_t)s * (DM / 2) + tid] = make_float2(px, py);
    }
    __syncthreads();
    if (tid < 48) {
        float S1 = 0.f, S2 = 0.f;
        for (int ww = 0; ww < 8; ++ww) { S1 += wpart[ww][tid][0]; S2 += wpart[ww][tid][1]; }
        float mean = S1 * (1.f / DM);
        float var = S2 * (1.f / DM) - mean * mean;
        float* st = stats + ((size_t)tid * SEQ + s) * 2;
        st[0] = mean;
        st[1] = rsqrtf(var + LNEPS);
    }
}

// ---------------------------------------------------------------------------
// K4: mid = prevpart + sum of masked attn-head rows (out rows 35..50) + stats.
// ---------------------------------------------------------------------------
__launch_bounds__(256, 2)
__global__ void k4_mlp_mask(const float* __restrict__ outp, const float* __restrict__ prevpart,
                            const float* __restrict__ mlpmaskf,
                            unsigned short* __restrict__ mid, float* __restrict__ stats) {
    int s = blockIdx.x, tid = threadIdx.x;
    int lane = tid & 63, w = tid >> 6;
    const float4* base = (const float4*)(outp + (size_t)s * OUTN * DM + 35 * DM);
    float4 acc = ((const float4*)prevpart)[(size_t)s * (DM / 4) + tid];
#pragma unroll 1
    for (int h = 0; h < NHEADS; ++h) {
        float mk = mlpmaskf[PN + h];          // uniform
        if (mk != 0.f) {
            float4 v = base[h * (DM / 4) + tid];
            acc.x += v.x; acc.y += v.y; acc.z += v.z; acc.w += v.w;
        }
    }
    unsigned int lo = (unsigned int)f2bf(acc.x) | ((unsigned int)f2bf(acc.y) << 16);
    unsigned int hi = (unsigned int)f2bf(acc.z) | ((unsigned int)f2bf(acc.w) << 16);
    ((uint2*)mid)[(size_t)s * (DM / 4) + tid] = make_uint2(lo, hi);
    float p1 = acc.x + acc.y + acc.z + acc.w;
    float p2 = acc.x * acc.x + acc.y * acc.y + acc.z * acc.z + acc.w * acc.w;
#pragma unroll
    for (int d = 1; d < 64; d <<= 1) { p1 += __shfl_xor(p1, d); p2 += __shfl_xor(p2, d); }
    __shared__ float wp[4][2];
    if (lane == 0) { wp[w][0] = p1; wp[w][1] = p2; }
    __syncthreads();
    if (tid == 0) {
        float S1 = wp[0][0] + wp[1][0] + wp[2][0] + wp[3][0];
        float S2 = wp[0][1] + wp[1][1] + wp[2][1] + wp[3][1];
        float mean = S1 * (1.f / DM);
        float var = S2 * (1.f / DM) - mean * mean;
        stats[s * 2] = mean;
        stats[s * 2 + 1] = rsqrtf(var + LNEPS);
    }
}

// ---------------------------------------------------------------------------
// m97-style bf16 GEMM: A MxK bf16 row-major, Bt NxK bf16 row-major (pre-
// transposed weights).  C = A * Bt^T.  global_load_lds(16B) staging into
// linear LDS, BK=64, 2-barrier loop.
// EPI 0: f32 out + bias*scale
// EPI 1: LN-affine + bias + rotary(q,k) + q*0.125 -> bf16   (QKV projection)
// EPI 2: LN-affine + bias + gelu -> bf16                    (MLP1)
// ---------------------------------------------------------------------------
template <int MF, int NF, int WGM, int WGN, int EPI>
__launch_bounds__(256, 2)
__global__ void gemm2(const unsigned short* __restrict__ A, size_t aZ, int lda,
                      const unsigned short* __restrict__ Bt, size_t bZ, int ldb,
                      float* __restrict__ Cf, unsigned short* __restrict__ Cb,
                      size_t cZ, int ldc,
                      const float* __restrict__ stats, size_t statsZ,
                      const float* __restrict__ colW, size_t colwZ,
                      const float* __restrict__ bias, size_t biasZ, float biasScale,
                      const float* __restrict__ rot, int K) {
    constexpr int BM = WGM * 16 * MF;
    constexpr int BN = WGN * 16 * NF;
    constexpr int nA = BM / 32;   // 1KB gload chunks per wave for A
    constexpr int nB = BN / 32;
    __shared__ unsigned short As[BM * 64];   // linear [row][64], 128B rows
    __shared__ unsigned short Bs[BN * 64];
    const int tid = threadIdx.x;
    const int lane = tid & 63;
    const int w = tid >> 6;
    const int wm = w % WGM, wn = w / WGM;
    const int z = blockIdx.z;
    const int m0 = blockIdx.x * BM;
    const int n0 = blockIdx.y * BN;
    const int cl = lane & 15, rq = lane >> 4;

    const unsigned short* Ab = A + (size_t)z * aZ + (size_t)m0 * lda;
    const unsigned short* Bb = Bt + (size_t)z * bZ + (size_t)n0 * ldb;
    const int lrow8 = lane >> 3, lcol8 = (lane & 7) * 8;

    f32x4 acc[MF][NF];
#pragma unroll
    for (int mf = 0; mf < MF; ++mf)
#pragma unroll
        for (int nf = 0; nf < NF; ++nf) acc[mf][nf] = 0.f;

    for (int k0 = 0; k0 < K; k0 += 64) {
        __syncthreads();
#pragma unroll
        for (int i = 0; i < nA; ++i) {
            int c = w * nA + i;
            int row = c * 8 + lrow8;
            gload_lds16(Ab + (size_t)row * lda + k0 + lcol8, (char*)As + c * 1024);
        }
#pragma unroll
        for (int i = 0; i < nB; ++i) {
            int c = w * nB + i;
            int row = c * 8 + lrow8;
            gload_lds16(Bb + (size_t)row * ldb + k0 + lcol8, (char*)Bs + c * 1024);
        }
        __syncthreads();
#pragma unroll
        for (int ks = 0; ks < 2; ++ks) {
            bf16x8 a[MF], b[NF];
#pragma unroll
            for (int mf = 0; mf < MF; ++mf)
                a[mf] = *(const bf16x8*)((const char*)As +
                        ((wm * MF + mf) * 16 + cl) * 128 + ks * 64 + rq * 16);
#pragma unroll
            for (int nf = 0; nf < NF; ++nf)
                b[nf] = *(const bf16x8*)((const char*)Bs +
                        ((wn * NF + nf) * 16 + cl) * 128 + ks * 64 + rq * 16);
#pragma unroll
            for (int mf = 0; mf < MF; ++mf)
#pragma unroll
                for (int nf = 0; nf < NF; ++nf)
                    acc[mf][nf] = __builtin_amdgcn_mfma_f32_16x16x32_bf16(a[mf], b[nf], acc[mf][nf], 0, 0, 0);
        }
    }

    if constexpr (EPI == 0) {
        float* Cz = Cf + (size_t)z * cZ;
        const float* bz = bias + (size_t)z * biasZ;
#pragma unroll
        for (int mf = 0; mf < MF; ++mf)
#pragma unroll
            for (int nf = 0; nf < NF; ++nf) {
                int col = n0 + wn * (16 * NF) + nf * 16 + cl;
                float bv = bz[col] * biasScale;
#pragma unroll
                for (int rr = 0; rr < 4; ++rr) {
                    int row = m0 + wm * (16 * MF) + mf * 16 + rq * 4 + rr;
                    Cz[(size_t)row * ldc + col] = acc[mf][nf][rr] + bv;
                }
            }
    } else if constexpr (EPI == 1) {
        unsigned short* Cz = Cb + (size_t)z * cZ;
        const int t = z >> 4;                      // 0=q 1=k 2=v
        const float qs = (t == 0) ? 0.125f : 1.f;  // fold 1/sqrt(D_HEAD)
        float vals[MF][NF][4];
        float meanv[MF][4], invv[MF][4];
#pragma unroll
        for (int mf = 0; mf < MF; ++mf)
#pragma unroll
            for (int rr = 0; rr < 4; ++rr) {
                int row = m0 + wm * (16 * MF) + mf * 16 + rq * 4 + rr;
                const float* st = stats + ((size_t)z * statsZ + row) * 2;
                meanv[mf][rr] = st[0];
                invv[mf][rr] = st[1];
            }
#pragma unroll
        for (int nf = 0; nf < NF; ++nf) {
            int col = n0 + wn * (16 * NF) + nf * 16 + cl;
            float cw = colW[(size_t)z * colwZ + col];
            float bv = bias[(size_t)z * biasZ + col];
#pragma unroll
            for (int mf = 0; mf < MF; ++mf)
#pragma unroll
                for (int rr = 0; rr < 4; ++rr)
                    vals[mf][nf][rr] = (acc[mf][nf][rr] - meanv[mf][rr] * cw) * invv[mf][rr] + bv;
        }
        if (t < 2) {   // rotary on q,k  (requires WGN==1, n0==0, NF==4 -> d pairs (nf, nf+2))
#pragma unroll
            for (int nf = 0; nf < NF / 2; ++nf) {
                int j = nf * 16 + cl;   // d_lo in [0,32)
#pragma unroll
                for (int mf = 0; mf < MF; ++mf)
#pragma unroll
                    for (int rr = 0; rr < 4; ++rr) {
                        int row = m0 + wm * (16 * MF) + mf * 16 + rq * 4 + rr;
                        float sn = rot[row * 64 + j];
                        float cs = rot[row * 64 + 32 + j];
                        float lo = vals[mf][nf][rr], hi = vals[mf][nf + 2][rr];
                        vals[mf][nf][rr] = lo * cs - hi * sn;
                        vals[mf][nf + 2][rr] = hi * cs + lo * sn;
                    }
            }
        }
#pragma unroll
        for (int mf = 0; mf < MF; ++mf)
#pragma unroll
            for (int nf = 0; nf < NF; ++nf) {
                int col = n0 + wn * (16 * NF) + nf * 16 + cl;
#pragma unroll
                for (int rr = 0; rr < 4; ++rr) {
                    int row = m0 + wm * (16 * MF) + mf * 16 + rq * 4 + rr;
                    Cz[(size_t)row * ldc + col] = f2bf(vals[mf][nf][rr] * qs);
                }
            }
    } else {  // EPI == 2 : LN-affine + bias + gelu -> bf16
        unsigned short* Cz = Cb;
#pragma unroll
        for (int mf = 0; mf < MF; ++mf)
#pragma unroll
            for (int rr = 0; rr < 4; ++rr) {
                int row = m0 + wm * (16 * MF) + mf * 16 + rq * 4 + rr;
                const float* st = stats + (size_t)row * 2;
                float mean = st[0], inv = st[1];
#pragma unroll
                for (int nf = 0; nf < NF; ++nf) {
                    int col = n0 + wn * (16 * NF) + nf * 16 + cl;
                    float x = (acc[mf][nf][rr] - mean * colW[col]) * inv + bias[col];
                    Cz[(size_t)row * ldc + col] = f2bf(gelu_tanh(x));
                }
            }
    }
}

// ---------------------------------------------------------------------------
// Flash attention: 16 heads, S=2048, D=64, causal.  q already scaled by 1/8.
// Block = 4 waves, 64 q-rows (16/wave), KV tiles of 64.
// ---------------------------------------------------------------------------
__launch_bounds__(256, 2)
__global__ void flash_k(const unsigned short* __restrict__ qkv,
                        unsigned short* __restrict__ zbuf) {
    const int qi = blockIdx.x, h = blockIdx.y;
    const int tid = threadIdx.x, lane = tid & 63, w = tid >> 6;
    const int cl = lane & 15, rq = lane >> 4;
    const unsigned short* qb = qkv;
    const unsigned short* kb = qkv + (size_t)NHEADS * SEQ * DH;
    const unsigned short* vb = kb + (size_t)NHEADS * SEQ * DH;
    const int q0 = qi * 64;

    __shared__ unsigned short Ks[64][72];
    __shared__ unsigned short Vt[64][72];
    __shared__ unsigned short Ps[64][72];

    bf16x8 aq[2];
    {
        int qrow = q0 + w * 16 + cl;
        const unsigned short* qp = qb + ((size_t)h * SEQ + qrow) * DH + rq * 8;
        aq[0] = *(const bf16x8*)(qp);
        aq[1] = *(const bf16x8*)(qp + 32);
    }
    float m_run[4] = {-3e38f, -3e38f, -3e38f, -3e38f};
    float l_run[4] = {0.f, 0.f, 0.f, 0.f};
    f32x4 accz[4];
#pragma unroll
    for (int nf = 0; nf < 4; ++nf) accz[nf] = 0.f;

    for (int j = 0; j <= qi; ++j) {
        __syncthreads();
        const unsigned short* kt = kb + ((size_t)h * SEQ + j * 64) * DH;
        const unsigned short* vt = vb + ((size_t)h * SEQ + j * 64) * DH;
#pragma unroll
        for (int i = 0; i < 2; ++i) {
            int idx = tid + i * 256;
            int row = idx >> 3, c8 = (idx & 7) * 8;
            *(u16x8*)&Ks[row][c8] = *(const u16x8*)(kt + (size_t)row * DH + c8);
            u16x8 v = *(const u16x8*)(vt + (size_t)row * DH + c8);
#pragma unroll
            for (int e = 0; e < 8; ++e) Vt[c8 + e][row] = v[e];
        }
        __syncthreads();

        f32x4 sfr[4];
#pragma unroll
        for (int nf = 0; nf < 4; ++nf) sfr[nf] = 0.f;
#pragma unroll
        for (int df = 0; df < 2; ++df)
#pragma unroll
            for (int nf = 0; nf < 4; ++nf) {
                bf16x8 b = *(const bf16x8*)&Ks[nf * 16 + cl][df * 32 + rq * 8];
                sfr[nf] = __builtin_amdgcn_mfma_f32_16x16x32_bf16(aq[df], b, sfr[nf], 0, 0, 0);
            }
        if (j == qi) {
#pragma unroll
            for (int nf = 0; nf < 4; ++nf)
#pragma unroll
                for (int rr = 0; rr < 4; ++rr) {
                    int qg = q0 + w * 16 + rq * 4 + rr;
                    int kg = j * 64 + nf * 16 + cl;
                    if (kg > qg) sfr[nf][rr] = -1e5f;
                }
        }
        float mnew[4], corr[4], psum[4];
#pragma unroll
        for (int rr = 0; rr < 4; ++rr) {
            float t0 = fmaxf(fmaxf(sfr[0][rr], sfr[1][rr]), fmaxf(sfr[2][rr], sfr[3][rr]));
            t0 = fmaxf(t0, __shfl_xor(t0, 1));
            t0 = fmaxf(t0, __shfl_xor(t0, 2));
            t0 = fmaxf(t0, __shfl_xor(t0, 4));
            t0 = fmaxf(t0, __shfl_xor(t0, 8));
            mnew[rr] = fmaxf(m_run[rr], t0);
            corr[rr] = exp2f((m_run[rr] - mnew[rr]) * L2E);
            psum[rr] = 0.f;
        }
#pragma unroll
        for (int nf = 0; nf < 4; ++nf)
#pragma unroll
            for (int rr = 0; rr < 4; ++rr) {
                float p = exp2f((sfr[nf][rr] - mnew[rr]) * L2E);
                sfr[nf][rr] = p;
                psum[rr] += p;
            }
#pragma unroll
        for (int rr = 0; rr < 4; ++rr) {
            float ps = psum[rr];
            ps += __shfl_xor(ps, 1);
            ps += __shfl_xor(ps, 2);
            ps += __shfl_xor(ps, 4);
            ps += __shfl_xor(ps, 8);
            l_run[rr] = l_run[rr] * corr[rr] + ps;
            m_run[rr] = mnew[rr];
        }
#pragma unroll
        for (int nf = 0; nf < 4; ++nf)
#pragma unroll
            for (int rr = 0; rr < 4; ++rr) accz[nf][rr] *= corr[rr];

        // P -> LDS (wave-private 16 rows), then consume as MFMA A operand
#pragma unroll
        for (int nf = 0; nf < 4; ++nf)
#pragma unroll
            for (int rr = 0; rr < 4; ++rr)
                Ps[w * 16 + rq * 4 + rr][nf * 16 + cl] = f2bf(sfr[nf][rr]);
#pragma unroll
        for (int ks = 0; ks < 2; ++ks) {
            bf16x8 ap = *(const bf16x8*)&Ps[w * 16 + cl][ks * 32 + rq * 8];
#pragma unroll
            for (int nf = 0; nf < 4; ++nf) {
                bf16x8 bv = *(const bf16x8*)&Vt[nf * 16 + cl][ks * 32 + rq * 8];
                accz[nf] = __builtin_amdgcn_mfma_f32_16x16x32_bf16(ap, bv, accz[nf], 0, 0, 0);
            }
        }
    }
#pragma unroll
    for (int nf = 0; nf < 4; ++nf)
#pragma unroll
        for (int rr = 0; rr < 4; ++rr) {
            int qg = q0 + w * 16 + rq * 4 + rr;
            zbuf[((size_t)h * SEQ + qg) * DH + nf * 16 + cl] = f2bf(accz[nf][rr] / l_run[rr]);
        }
}

// ---------------------------------------------------------------------------
extern "C" void kernel_launch(void* const* d_in, const int* in_sizes, int n_in,
                              void* d_out, int out_size, void* d_ws, size_t ws_size,
                              hipStream_t stream) {
    const float* resid = (const float*)d_in[0];
    const float* W_Q = (const float*)d_in[1];
    const float* b_Q = (const float*)d_in[2];
    const float* W_K = (const float*)d_in[3];
    const float* b_K = (const float*)d_in[4];
    const float* W_V = (const float*)d_in[5];
    const float* b_V = (const float*)d_in[6];
    const float* W_O = (const float*)d_in[7];
    const float* b_O = (const float*)d_in[8];
    const float* mql = (const float*)d_in[9];
    const float* mkl = (const float*)d_in[10];
    const float* mvl = (const float*)d_in[11];
    const float* mml = (const float*)d_in[12];
    const float* W_in = (const float*)d_in[13];
    const float* b_in = (const float*)d_in[14];
    const float* W_out = (const float*)d_in[15];
    const float* b_out = (const float*)d_in[16];
    float* out = (float*)d_out;
    (void)in_sizes; (void)n_in; (void)out_size; (void)ws_size;

    char* ws = (char*)d_ws;
    size_t off = 0;
    auto carve = [&](size_t bytes) -> void* {
        void* p = ws + off;
        off += (bytes + 255) & ~(size_t)255;
        return p;
    };
    unsigned short* nrm = (unsigned short*)carve((size_t)48 * SEQ * DM * 2);  // 192 MB
    float* statsQ = (float*)carve((size_t)48 * SEQ * 2 * 4);
    unsigned short* qkv = (unsigned short*)carve((size_t)48 * SEQ * DH * 2);
    unsigned short* zbuf = (unsigned short*)carve((size_t)NHEADS * SEQ * DH * 2);
    unsigned short* mid = (unsigned short*)carve((size_t)SEQ * DM * 2);
    float* statsM = (float*)carve((size_t)SEQ * 2 * 4);
    unsigned short* act = (unsigned short*)carve((size_t)SEQ * DMLP * 2);
    float* rot = (float*)carve((size_t)SEQ * 64 * 4);
    float* colWqkv = (float*)carve((size_t)48 * 64 * 4);
    float* colWin = (float*)carve((size_t)DMLP * 4);
    float* maskP2 = (float*)carve((size_t)48 * 64 * 4);
    float* mlpmaskf = (float*)carve((size_t)64 * 4);
    float* biasQKV = (float*)carve((size_t)48 * 64 * 4);
    float* prevpart = (float*)carve((size_t)SEQ * DM * 4);                    // 8 MB
    unsigned short* WtQKV = (unsigned short*)carve((size_t)48 * DH * DM * 2); // 6 MB
    unsigned short* WtO = (unsigned short*)carve((size_t)16 * DM * DH * 2);   // 2 MB
    unsigned short* WtIn = (unsigned short*)carve((size_t)DMLP * DM * 2);     // 8 MB
    unsigned short* WtOut = (unsigned short*)carve((size_t)DM * DMLP * 2);    // 8 MB
    // total ~265 MB of d_ws

    prep_masks<<<1, 64, 0, stream>>>(mql, mkl, mvl, mml, b_Q, b_K, b_V, maskP2, mlpmaskf, biasQKV);
    prep_rotary<<<256, 256, 0, stream>>>(rot);
    colsum_k<<<dim3(1, 16), 256, 0, stream>>>(W_Q, colWqkv, 1024, 64);
    colsum_k<<<dim3(1, 16), 256, 0, stream>>>(W_K, colWqkv + 1024, 1024, 64);
    colsum_k<<<dim3(1, 16), 256, 0, stream>>>(W_V, colWqkv + 2048, 1024, 64);
    colsum_k<<<dim3(64, 1), 256, 0, stream>>>(W_in, colWin, 1024, DMLP);

    // weight transpose+convert to bf16 NxK
    wtrans<<<dim3(2, 32, 16), 256, 0, stream>>>(W_Q, WtQKV, DM, DH, (size_t)DM * DH, (size_t)DH * DM);
    wtrans<<<dim3(2, 32, 16), 256, 0, stream>>>(W_K, WtQKV + (size_t)16 * DH * DM, DM, DH, (size_t)DM * DH, (size_t)DH * DM);
    wtrans<<<dim3(2, 32, 16), 256, 0, stream>>>(W_V, WtQKV + (size_t)32 * DH * DM, DM, DH, (size_t)DM * DH, (size_t)DH * DM);
    wtrans<<<dim3(32, 2, 16), 256, 0, stream>>>(W_O, WtO, DH, DM, (size_t)DH * DM, (size_t)DM * DH);
    wtrans<<<dim3(128, 32, 1), 256, 0, stream>>>(W_in, WtIn, DM, DMLP, 0, 0);
    wtrans<<<dim3(32, 128, 1), 256, 0, stream>>>(W_out, WtOut, DMLP, DM, 0, 0);

    k1_masked_norm<<<SEQ, 512, 0, stream>>>(resid, maskP2, mlpmaskf, out, nrm, statsQ, prevpart);

    // QKV projection: 48 GEMMs (2048x1024x64), LN fold + bias + rotary + q*0.125
    gemm2<2, 4, 4, 1, 1><<<dim3(16, 1, 48), 256, 0, stream>>>(
        nrm, (size_t)SEQ * DM, DM,
        WtQKV, (size_t)DH * DM, DM,
        nullptr, qkv, (size_t)SEQ * DH, DH,
        statsQ, SEQ,
        colWqkv, 64,
        biasQKV, 64, 1.f,
        rot, DM);

    flash_k<<<dim3(32, 16), 256, 0, stream>>>(qkv, zbuf);

    // attn_out per head: (2048x64)@(64x1024) + b_O/16 -> d_out rows 35..50
    gemm2<4, 4, 2, 2, 0><<<dim3(16, 8, 16), 256, 0, stream>>>(
        zbuf, (size_t)SEQ * DH, DH,
        WtO, (size_t)DM * DH, DH,
        out + 35 * DM, nullptr, (size_t)DM, OUTN * DM,
        nullptr, 0, nullptr, 0,
        b_O, 0, 1.f / 16.f,
        nullptr, DH);

    k4_mlp_mask<<<SEQ, 256, 0, stream>>>(out, prevpart, mlpmaskf, mid, statsM);

    // MLP1: (2048x1024)@(1024x4096), LN fold + b_in + gelu -> act
    gemm2<4, 4, 2, 2, 2><<<dim3(16, 32, 1), 256, 0, stream>>>(
        mid, 0, DM,
        WtIn, 0, DM,
        nullptr, act, 0, DMLP,
        statsM, 0,
        colWin, 0,
        b_in, 0, 1.f,
        nullptr, DM);

    // MLP2: (2048x4096)@(4096x1024) + b_out -> d_out row 51
    gemm2<2, 4, 2, 2, 0><<<dim3(32, 8, 1), 256, 0, stream>>>(
        act, 0, DMLP,
        WtOut, 0, DMLP,
        out + 51 * DM, nullptr, 0, OUTN * DM,
        nullptr, 0, nullptr, 0,
        b_out, 0, 1.f,
        nullptr, DMLP);
}

// Round 3
// 578.513 us; speedup vs baseline: 2.1705x; 1.6908x over previous
//
#include <hip/hip_runtime.h>
#include <stdint.h>

// ---------------------------------------------------------------------------
// TransformerBlock (masked-subnetwork block) for MI355X / gfx950.  Round 3:
//  - flash: balanced q-tile pairs {qi, 31-qi}; V pre-transposed in global,
//    staged with global_load_lds (no scalar LDS transpose).
//  - attn-out GEMM fused over all 16 heads + masked MLP-residual accumulation
//    (replaces k4's 134 MB re-read).
//  - XOR-granule LDS swizzle (pre-swizzled global src + swizzled read) on all
//    MFMA staging tiles -> 16-way ds_read_b128 conflicts become 2-way.
//  - k1 masks as uniform u64 bitmaps; prep consolidated; colsums folded into
//    weight-transpose kernels (atomicAdd).
// ---------------------------------------------------------------------------

#define SEQ 2048
#define DM 1024
#define NHEADS 16
#define DH 64
#define DMLP 4096
#define PN 35
#define TOTN 51
#define OUTN 52
#define LNEPS 1e-5f
#define L2E 1.44269504088896340736f

typedef __bf16 bf16x8 __attribute__((ext_vector_type(8)));
typedef float f32x4 __attribute__((ext_vector_type(4)));
typedef unsigned short u16x8 __attribute__((ext_vector_type(8)));

static __device__ __forceinline__ unsigned short f2bf(float f) {
    unsigned int u = __builtin_bit_cast(unsigned int, f);
    u += 0x7fffu + ((u >> 16) & 1u);
    return (unsigned short)(u >> 16);
}

static __device__ __forceinline__ float gelu_tanh(float x) {
    float u = 0.7978845608028654f * x * (1.f + 0.044715f * x * x);
    float e = exp2f(u * (2.f * L2E));          // e^{2u}
    float th = 1.f - 2.f / (e + 1.f);          // tanh(u)
    return 0.5f * x * (1.f + th);
}

// async global->LDS, 16B per lane; lds dest wave-uniform base + lane*16.
static __device__ __forceinline__ void gload_lds16(const void* g, void* l) {
    __builtin_amdgcn_global_load_lds(
        (const __attribute__((address_space(1))) unsigned int*)g,
        (__attribute__((address_space(3))) unsigned int*)l, 16, 0, 0);
}

// XOR-granule swizzle: LDS[row][g] holds global[row][g ^ (row&7)], g = 16B
// granule within a 128B row.  Staging source column (in shorts) for a lane:
static __device__ __forceinline__ int swz_src(int lane) {
    return ((lane & 7) ^ ((lane >> 3) & 7)) * 8;
}
// read-side byte offset within the row for logical granule g of row r:
static __device__ __forceinline__ int swz_off(int r, int g) {
    return ((g ^ (r & 7)) * 16);
}

// ---------------------------------------------------------------------------
// prep: rotary table, mask bitmaps, biases, zero colsum buffers.  grid 260.
// ---------------------------------------------------------------------------
__global__ void prep_all(const float* __restrict__ mq, const float* __restrict__ mk,
                         const float* __restrict__ mv, const float* __restrict__ mmlp,
                         const float* __restrict__ bQ, const float* __restrict__ bK,
                         const float* __restrict__ bV,
                         float* __restrict__ rot, unsigned long long* __restrict__ maskbits,
                         float* __restrict__ mlpmaskf, float* __restrict__ biasQKV,
                         float* __restrict__ colWqkv, float* __restrict__ colWin) {
    int bid = blockIdx.x, tid = threadIdx.x;
    if (bid < 256) {
        int id = bid * 256 + tid;            // 2048*32
        int s = id >> 5, j = id & 31;
        float freq = powf(10000.f, (float)j * (1.f / 32.f));
        float ang = (float)s / freq;
        rot[s * 64 + j] = sinf(ang);
        rot[s * 64 + 32 + j] = cosf(ang);
    } else if (bid == 256) {
        if (tid < 48) {
            int ty = tid >> 4, h = tid & 15;
            const float* src = (ty == 0) ? mq : (ty == 1 ? mk : mv);
            unsigned long long bits = 0;
            for (int n = 0; n < PN; ++n)
                if (src[n * NHEADS + h] > 0.f) bits |= 1ull << n;
            maskbits[tid] = bits;
            const float* bsrc = (ty == 0) ? bQ : (ty == 1 ? bK : bV);
            for (int d = 0; d < DH; ++d) biasQKV[tid * 64 + d] = bsrc[h * DH + d];
        }
        if (tid == 48) {
            unsigned long long bits = 0;
            for (int n = 0; n < PN; ++n)
                if (mmlp[n] > 0.f) bits |= 1ull << n;
            maskbits[48] = bits;
        }
        if (tid < 64) mlpmaskf[tid] = (tid < TOTN && mmlp[tid] > 0.f) ? 1.f : 0.f;
    } else if (bid == 257) {
        for (int i = tid; i < 3072; i += 256) colWqkv[i] = 0.f;
    } else {
        int base = (bid - 258) * 2048;
        for (int i = tid; i < 2048; i += 256) colWin[base + i] = 0.f;
    }
}

// ---------------------------------------------------------------------------
// transpose+convert: in f32 KxN row-major -> out bf16 NxK row-major (per z);
// optionally accumulates column sums (over K) into colsum[z*colZ + n].
// ---------------------------------------------------------------------------
__global__ void wtrans(const float* __restrict__ in, unsigned short* __restrict__ out,
                       int K, int N, size_t inZ, size_t outZ,
                       float* __restrict__ colsum, size_t colZ) {
    int z = blockIdx.z;
    const float* ib = in + (size_t)z * inZ;
    unsigned short* ob = out + (size_t)z * outZ;
    __shared__ float t[32][33];
    int n0 = blockIdx.x * 32, k0 = blockIdx.y * 32;
    int tx = threadIdx.x & 31, ty = threadIdx.x >> 5;   // 32x8
#pragma unroll
    for (int r = 0; r < 4; ++r) {
        int k = ty + r * 8;
        t[k][tx] = ib[(size_t)(k0 + k) * N + n0 + tx];
    }
    __syncthreads();
#pragma unroll
    for (int r = 0; r < 4; ++r) {
        int n = ty + r * 8;
        ob[(size_t)(n0 + n) * K + k0 + tx] = f2bf(t[tx][n]);
    }
    if (colsum != nullptr && ty == 0) {
        float s = 0.f;
#pragma unroll
        for (int k = 0; k < 32; ++k) s += t[k][tx];
        atomicAdd(&colsum[(size_t)z * colZ + n0 + tx], s);
    }
}

// ---------------------------------------------------------------------------
// K1: per position s: copy resid_pre -> out rows 0..34, 48 masked sums (bf16)
// + LN stats, and the masked-prev-node MLP partial (f32).
// ---------------------------------------------------------------------------
__launch_bounds__(512, 1)
__global__ void k1_masked_norm(const float* __restrict__ resid,
                               const unsigned long long* __restrict__ maskbits,
                               float* __restrict__ outp,
                               unsigned short* __restrict__ nrm,
                               float* __restrict__ stats,
                               float* __restrict__ prevpart) {
    int s = blockIdx.x;
    int tid = threadIdx.x;
    int lane = tid & 63, w = tid >> 6;
    const float2* rp = (const float2*)(resid + (size_t)s * PN * DM);
    float2* outv = (float2*)(outp + (size_t)s * OUTN * DM);
    float2 r[PN];
#pragma unroll
    for (int n = 0; n < PN; ++n) {
        float2 v = rp[n * (DM / 2) + tid];
        r[n] = v;
        outv[n * (DM / 2) + tid] = v;
    }
    __shared__ float wpart[8][48][2];
#pragma unroll 1
    for (int th = 0; th < 48; ++th) {
        unsigned long long bits = maskbits[th];   // uniform
        float sx = 0.f, sy = 0.f;
#pragma unroll
        for (int n = 0; n < PN; ++n) {
            if ((bits >> n) & 1ull) { sx += r[n].x; sy += r[n].y; }
        }
        unsigned int pk = (unsigned int)f2bf(sx) | ((unsigned int)f2bf(sy) << 16);
        ((unsigned int*)nrm)[((size_t)th * SEQ + s) * (DM / 2) + tid] = pk;
        float p1 = sx + sy, p2 = sx * sx + sy * sy;
#pragma unroll
        for (int d = 1; d < 64; d <<= 1) {
            p1 += __shfl_xor(p1, d);
            p2 += __shfl_xor(p2, d);
        }
        if (lane == 0) { wpart[w][th][0] = p1; wpart[w][th][1] = p2; }
    }
    {
        unsigned long long bits = maskbits[48];
        float px = 0.f, py = 0.f;
#pragma unroll
        for (int n = 0; n < PN; ++n) {
            if ((bits >> n) & 1ull) { px += r[n].x; py += r[n].y; }
        }
        ((float2*)prevpart)[(size_t)s * (DM / 2) + tid] = make_float2(px, py);
    }
    __syncthreads();
    if (tid < 48) {
        float S1 = 0.f, S2 = 0.f;
        for (int ww = 0; ww < 8; ++ww) { S1 += wpart[ww][tid][0]; S2 += wpart[ww][tid][1]; }
        float mean = S1 * (1.f / DM);
        float var = S2 * (1.f / DM) - mean * mean;
        float* st = stats + ((size_t)tid * SEQ + s) * 2;
        st[0] = mean;
        st[1] = rsqrtf(var + LNEPS);
    }
}

// ---------------------------------------------------------------------------
// stats of mid rows (f32, 2048x1024) -> statsM
// ---------------------------------------------------------------------------
__launch_bounds__(256, 4)
__global__ void stats_k(const float* __restrict__ midf, float* __restrict__ stats) {
    int s = blockIdx.x, tid = threadIdx.x;
    int lane = tid & 63, w = tid >> 6;
    float4 v = ((const float4*)midf)[(size_t)s * (DM / 4) + tid];
    float p1 = v.x + v.y + v.z + v.w;
    float p2 = v.x * v.x + v.y * v.y + v.z * v.z + v.w * v.w;
#pragma unroll
    for (int d = 1; d < 64; d <<= 1) { p1 += __shfl_xor(p1, d); p2 += __shfl_xor(p2, d); }
    __shared__ float wp[4][2];
    if (lane == 0) { wp[w][0] = p1; wp[w][1] = p2; }
    __syncthreads();
    if (tid == 0) {
        float S1 = wp[0][0] + wp[1][0] + wp[2][0] + wp[3][0];
        float S2 = wp[0][1] + wp[1][1] + wp[2][1] + wp[3][1];
        float mean = S1 * (1.f / DM);
        float var = S2 * (1.f / DM) - mean * mean;
        stats[s * 2] = mean;
        stats[s * 2 + 1] = rsqrtf(var + LNEPS);
    }
}

// ---------------------------------------------------------------------------
// m97-style bf16 GEMM: A MxK bf16 row-major, Bt NxK bf16 row-major.
// C = A*Bt^T.  gload_lds(16B) staging, XOR-granule swizzled LDS, BK=64.
// EPI 0: f32 out + bias*scale
// EPI 1: LN-affine + bias + rotary(q,k) + q*0.125 -> bf16; V written
//        transposed [h][d][s] to Vt.
// EPI 2: LN-affine + bias + gelu -> bf16
// ---------------------------------------------------------------------------
template <int MF, int NF, int WGM, int WGN, int EPI>
__launch_bounds__(256, 2)
__global__ void gemm2(const unsigned short* __restrict__ A, size_t aZ, int lda,
                      const unsigned short* __restrict__ Bt, size_t bZ, int ldb,
                      float* __restrict__ Cf, unsigned short* __restrict__ Cb,
                      size_t cZ, int ldc,
                      const float* __restrict__ stats, size_t statsZ,
                      const float* __restrict__ colW, size_t colwZ,
                      const float* __restrict__ bias, size_t biasZ, float biasScale,
                      const float* __restrict__ rot, unsigned short* __restrict__ Vt,
                      int K) {
    constexpr int BM = WGM * 16 * MF;
    constexpr int BN = WGN * 16 * NF;
    constexpr int nA = BM / 32;
    constexpr int nB = BN / 32;
    __shared__ unsigned short As[BM * 64];   // linear 128B rows, swizzled granules
    __shared__ unsigned short Bs[BN * 64];
    const int tid = threadIdx.x;
    const int lane = tid & 63;
    const int w = tid >> 6;
    const int wm = w % WGM, wn = w / WGM;
    const int z = blockIdx.z;
    const int m0 = blockIdx.x * BM;
    const int n0 = blockIdx.y * BN;
    const int cl = lane & 15, rq = lane >> 4;

    const unsigned short* Ab = A + (size_t)z * aZ + (size_t)m0 * lda;
    const unsigned short* Bb = Bt + (size_t)z * bZ + (size_t)n0 * ldb;
    const int lrow8 = lane >> 3;
    const int scol = swz_src(lane);

    f32x4 acc[MF][NF];
#pragma unroll
    for (int mf = 0; mf < MF; ++mf)
#pragma unroll
        for (int nf = 0; nf < NF; ++nf) acc[mf][nf] = 0.f;

    for (int k0 = 0; k0 < K; k0 += 64) {
        __syncthreads();
#pragma unroll
        for (int i = 0; i < nA; ++i) {
            int c = w * nA + i;
            int row = c * 8 + lrow8;
            gload_lds16(Ab + (size_t)row * lda + k0 + scol, (char*)As + c * 1024);
        }
#pragma unroll
        for (int i = 0; i < nB; ++i) {
            int c = w * nB + i;
            int row = c * 8 + lrow8;
            gload_lds16(Bb + (size_t)row * ldb + k0 + scol, (char*)Bs + c * 1024);
        }
        __syncthreads();
#pragma unroll
        for (int ks = 0; ks < 2; ++ks) {
            bf16x8 a[MF], b[NF];
#pragma unroll
            for (int mf = 0; mf < MF; ++mf) {
                int ra = (wm * MF + mf) * 16 + cl;
                a[mf] = *(const bf16x8*)((const char*)As + ra * 128 + swz_off(cl, ks * 4 + rq));
            }
#pragma unroll
            for (int nf = 0; nf < NF; ++nf) {
                int rb = (wn * NF + nf) * 16 + cl;
                b[nf] = *(const bf16x8*)((const char*)Bs + rb * 128 + swz_off(cl, ks * 4 + rq));
            }
#pragma unroll
            for (int mf = 0; mf < MF; ++mf)
#pragma unroll
                for (int nf = 0; nf < NF; ++nf)
                    acc[mf][nf] = __builtin_amdgcn_mfma_f32_16x16x32_bf16(a[mf], b[nf], acc[mf][nf], 0, 0, 0);
        }
    }

    if constexpr (EPI == 0) {
        float* Cz = Cf + (size_t)z * cZ;
        const float* bz = bias + (size_t)z * biasZ;
#pragma unroll
        for (int mf = 0; mf < MF; ++mf)
#pragma unroll
            for (int nf = 0; nf < NF; ++nf) {
                int col = n0 + wn * (16 * NF) + nf * 16 + cl;
                float bv = bz[col] * biasScale;
#pragma unroll
                for (int rr = 0; rr < 4; ++rr) {
                    int row = m0 + wm * (16 * MF) + mf * 16 + rq * 4 + rr;
                    Cz[(size_t)row * ldc + col] = acc[mf][nf][rr] + bv;
                }
            }
    } else if constexpr (EPI == 1) {
        const int t = z >> 4;                      // 0=q 1=k 2=v
        const int h = z & 15;
        const float qs = (t == 0) ? 0.125f : 1.f;
        float vals[MF][NF][4];
        float meanv[MF][4], invv[MF][4];
#pragma unroll
        for (int mf = 0; mf < MF; ++mf)
#pragma unroll
            for (int rr = 0; rr < 4; ++rr) {
                int row = m0 + wm * (16 * MF) + mf * 16 + rq * 4 + rr;
                const float* st = stats + ((size_t)z * statsZ + row) * 2;
                meanv[mf][rr] = st[0];
                invv[mf][rr] = st[1];
            }
#pragma unroll
        for (int nf = 0; nf < NF; ++nf) {
            int col = n0 + wn * (16 * NF) + nf * 16 + cl;
            float cw = colW[(size_t)z * colwZ + col];
            float bv = bias[(size_t)z * biasZ + col];
#pragma unroll
            for (int mf = 0; mf < MF; ++mf)
#pragma unroll
                for (int rr = 0; rr < 4; ++rr)
                    vals[mf][nf][rr] = (acc[mf][nf][rr] - meanv[mf][rr] * cw) * invv[mf][rr] + bv;
        }
        if (t < 2) {   // rotary on q,k  (WGN==1, n0==0, NF==4 -> pairs (nf, nf+2))
#pragma unroll
            for (int nf = 0; nf < NF / 2; ++nf) {
                int j = nf * 16 + cl;
#pragma unroll
                for (int mf = 0; mf < MF; ++mf)
#pragma unroll
                    for (int rr = 0; rr < 4; ++rr) {
                        int row = m0 + wm * (16 * MF) + mf * 16 + rq * 4 + rr;
                        float sn = rot[row * 64 + j];
                        float cs = rot[row * 64 + 32 + j];
                        float lo = vals[mf][nf][rr], hi = vals[mf][nf + 2][rr];
                        vals[mf][nf][rr] = lo * cs - hi * sn;
                        vals[mf][nf + 2][rr] = hi * cs + lo * sn;
                    }
            }
        }
        if (t == 2) {
            // V: write transposed [h][d][s], 4 consecutive s packed per store
#pragma unroll
            for (int mf = 0; mf < MF; ++mf)
#pragma unroll
                for (int nf = 0; nf < NF; ++nf) {
                    int col = nf * 16 + cl;   // d
                    int row0 = m0 + wm * (16 * MF) + mf * 16 + rq * 4;
                    ushort4 pk;
                    pk.x = f2bf(vals[mf][nf][0]);
                    pk.y = f2bf(vals[mf][nf][1]);
                    pk.z = f2bf(vals[mf][nf][2]);
                    pk.w = f2bf(vals[mf][nf][3]);
                    *(ushort4*)&Vt[((size_t)h * DH + col) * SEQ + row0] = pk;
                }
        } else {
            unsigned short* Cz = Cb + (size_t)z * cZ;
#pragma unroll
            for (int mf = 0; mf < MF; ++mf)
#pragma unroll
                for (int nf = 0; nf < NF; ++nf) {
                    int col = n0 + wn * (16 * NF) + nf * 16 + cl;
#pragma unroll
                    for (int rr = 0; rr < 4; ++rr) {
                        int row = m0 + wm * (16 * MF) + mf * 16 + rq * 4 + rr;
                        Cz[(size_t)row * ldc + col] = f2bf(vals[mf][nf][rr] * qs);
                    }
                }
        }
    } else {  // EPI == 2 : LN-affine + bias + gelu -> bf16
        unsigned short* Cz = Cb;
#pragma unroll
        for (int mf = 0; mf < MF; ++mf)
#pragma unroll
            for (int rr = 0; rr < 4; ++rr) {
                int row = m0 + wm * (16 * MF) + mf * 16 + rq * 4 + rr;
                const float* st = stats + (size_t)row * 2;
                float mean = st[0], inv = st[1];
#pragma unroll
                for (int nf = 0; nf < NF; ++nf) {
                    int col = n0 + wn * (16 * NF) + nf * 16 + cl;
                    float x = (acc[mf][nf][rr] - mean * colW[col]) * inv + bias[col];
                    Cz[(size_t)row * ldc + col] = f2bf(gelu_tanh(x));
                }
            }
    }
}

// ---------------------------------------------------------------------------
// Flash attention: balanced pairs {p, 31-p} of 64-row q-tiles, 16 heads.
// K staged [k][d], V^T staged [d][k], both via gload_lds with swizzle.
// ---------------------------------------------------------------------------
__launch_bounds__(256, 2)
__global__ void flash_k(const unsigned short* __restrict__ qkv,
                        const unsigned short* __restrict__ vt,
                        unsigned short* __restrict__ zbuf) {
    const int p = blockIdx.x, h = blockIdx.y;
    const int tid = threadIdx.x, lane = tid & 63, w = tid >> 6;
    const int cl = lane & 15, rq = lane >> 4;
    const int lrow8 = lane >> 3;
    const int scol = swz_src(lane);
    const unsigned short* qb = qkv + ((size_t)h * SEQ) * DH;
    const unsigned short* kb = qkv + ((size_t)(16 + h) * SEQ) * DH;
    const unsigned short* vtb = vt + (size_t)h * DH * SEQ;

    __shared__ unsigned short Ks[64 * 64];   // [k][d] swizzled
    __shared__ unsigned short Vs[64 * 64];   // [d][k] swizzled
    __shared__ unsigned short Ps[64][72];    // padded, scalar writes

#pragma unroll 1
    for (int half = 0; half < 2; ++half) {
        const int qi = half ? (31 - p) : p;
        const int q0 = qi * 64;

        bf16x8 aq[2];
        {
            int qrow = q0 + w * 16 + cl;
            const unsigned short* qp = qb + (size_t)qrow * DH + rq * 8;
            aq[0] = *(const bf16x8*)(qp);
            aq[1] = *(const bf16x8*)(qp + 32);
        }
        float m_run[4] = {-3e38f, -3e38f, -3e38f, -3e38f};
        float l_run[4] = {0.f, 0.f, 0.f, 0.f};
        f32x4 accz[4];
#pragma unroll
        for (int nf = 0; nf < 4; ++nf) accz[nf] = 0.f;

#pragma unroll 1
        for (int j = 0; j <= qi; ++j) {
            __syncthreads();
#pragma unroll
            for (int i = 0; i < 2; ++i) {
                int c = w * 2 + i;
                int row = c * 8 + lrow8;
                gload_lds16(kb + (size_t)(j * 64 + row) * DH + scol, (char*)Ks + c * 1024);
                gload_lds16(vtb + (size_t)row * SEQ + j * 64 + scol, (char*)Vs + c * 1024);
            }
            __syncthreads();

            f32x4 sfr[4];
#pragma unroll
            for (int nf = 0; nf < 4; ++nf) sfr[nf] = 0.f;
#pragma unroll
            for (int df = 0; df < 2; ++df)
#pragma unroll
                for (int nf = 0; nf < 4; ++nf) {
                    int rb = nf * 16 + cl;
                    bf16x8 b = *(const bf16x8*)((const char*)Ks + rb * 128 + swz_off(cl, df * 4 + rq));
                    sfr[nf] = __builtin_amdgcn_mfma_f32_16x16x32_bf16(aq[df], b, sfr[nf], 0, 0, 0);
                }
            if (j == qi) {
#pragma unroll
                for (int nf = 0; nf < 4; ++nf)
#pragma unroll
                    for (int rr = 0; rr < 4; ++rr) {
                        int qg = q0 + w * 16 + rq * 4 + rr;
                        int kg = j * 64 + nf * 16 + cl;
                        if (kg > qg) sfr[nf][rr] = -1e5f;
                    }
            }
            float mnew[4], corr[4], psum[4];
#pragma unroll
            for (int rr = 0; rr < 4; ++rr) {
                float t0 = fmaxf(fmaxf(sfr[0][rr], sfr[1][rr]), fmaxf(sfr[2][rr], sfr[3][rr]));
                t0 = fmaxf(t0, __shfl_xor(t0, 1));
                t0 = fmaxf(t0, __shfl_xor(t0, 2));
                t0 = fmaxf(t0, __shfl_xor(t0, 4));
                t0 = fmaxf(t0, __shfl_xor(t0, 8));
                mnew[rr] = fmaxf(m_run[rr], t0);
                corr[rr] = exp2f((m_run[rr] - mnew[rr]) * L2E);
                psum[rr] = 0.f;
            }
#pragma unroll
            for (int nf = 0; nf < 4; ++nf)
#pragma unroll
                for (int rr = 0; rr < 4; ++rr) {
                    float pv = exp2f((sfr[nf][rr] - mnew[rr]) * L2E);
                    sfr[nf][rr] = pv;
                    psum[rr] += pv;
                }
#pragma unroll
            for (int rr = 0; rr < 4; ++rr) {
                float ps = psum[rr];
                ps += __shfl_xor(ps, 1);
                ps += __shfl_xor(ps, 2);
                ps += __shfl_xor(ps, 4);
                ps += __shfl_xor(ps, 8);
                l_run[rr] = l_run[rr] * corr[rr] + ps;
                m_run[rr] = mnew[rr];
            }
#pragma unroll
            for (int nf = 0; nf < 4; ++nf)
#pragma unroll
                for (int rr = 0; rr < 4; ++rr) accz[nf][rr] *= corr[rr];

#pragma unroll
            for (int nf = 0; nf < 4; ++nf)
#pragma unroll
                for (int rr = 0; rr < 4; ++rr)
                    Ps[w * 16 + rq * 4 + rr][nf * 16 + cl] = f2bf(sfr[nf][rr]);
#pragma unroll
            for (int ks = 0; ks < 2; ++ks) {
                bf16x8 ap = *(const bf16x8*)&Ps[w * 16 + cl][ks * 32 + rq * 8];
#pragma unroll
                for (int nf = 0; nf < 4; ++nf) {
                    int rb = nf * 16 + cl;
                    bf16x8 bv = *(const bf16x8*)((const char*)Vs + rb * 128 + swz_off(cl, ks * 4 + rq));
                    accz[nf] = __builtin_amdgcn_mfma_f32_16x16x32_bf16(ap, bv, accz[nf], 0, 0, 0);
                }
            }
        }
#pragma unroll
        for (int nf = 0; nf < 4; ++nf)
#pragma unroll
            for (int rr = 0; rr < 4; ++rr) {
                int qg = q0 + w * 16 + rq * 4 + rr;
                zbuf[((size_t)h * SEQ + qg) * DH + nf * 16 + cl] = f2bf(accz[nf][rr] / l_run[rr]);
            }
        __syncthreads();   // protect LDS before next half re-stages
    }
}

// ---------------------------------------------------------------------------
// Fused attn-out: per block (64 s-rows x 128 model cols), loop 16 heads:
// GEMM z_h @ W_O_h + b_O/16 -> out row 35+h, accumulate masked MLP residual,
// add prevpart, write mid (bf16 + f32).
// ---------------------------------------------------------------------------
__launch_bounds__(256, 2)
__global__ void attn_fused(const unsigned short* __restrict__ zbuf,
                           const unsigned short* __restrict__ WtO,
                           const float* __restrict__ bO,
                           const float* __restrict__ mlpmaskf,
                           const float* __restrict__ prevpart,
                           float* __restrict__ outp,
                           unsigned short* __restrict__ midb,
                           float* __restrict__ midf) {
    __shared__ unsigned short As[64 * 64];    // z tile [s][d]
    __shared__ unsigned short Bs[128 * 64];   // W_O^T tile [m][d]
    const int tid = threadIdx.x;
    const int lane = tid & 63;
    const int w = tid >> 6;          // WGM=1, WGN=4 -> wn = w
    const int cl = lane & 15, rq = lane >> 4;
    const int lrow8 = lane >> 3;
    const int scol = swz_src(lane);
    const int m0 = blockIdx.x * 64;
    const int n0 = blockIdx.y * 128;

    f32x4 macc[4][2];
#pragma unroll
    for (int mf = 0; mf < 4; ++mf)
#pragma unroll
        for (int nf = 0; nf < 2; ++nf)
#pragma unroll
            for (int rr = 0; rr < 4; ++rr) {
                int row = m0 + mf * 16 + rq * 4 + rr;
                int col = n0 + w * 32 + nf * 16 + cl;
                macc[mf][nf][rr] = prevpart[(size_t)row * DM + col];
            }

#pragma unroll 1
    for (int h = 0; h < NHEADS; ++h) {
        __syncthreads();
#pragma unroll
        for (int i = 0; i < 2; ++i) {
            int c = w * 2 + i;
            int row = c * 8 + lrow8;
            gload_lds16(zbuf + ((size_t)h * SEQ + m0 + row) * DH + scol, (char*)As + c * 1024);
        }
#pragma unroll
        for (int i = 0; i < 4; ++i) {
            int c = w * 4 + i;
            int row = c * 8 + lrow8;
            gload_lds16(WtO + ((size_t)h * DM + n0 + row) * DH + scol, (char*)Bs + c * 1024);
        }
        __syncthreads();
        f32x4 acc[4][2];
#pragma unroll
        for (int mf = 0; mf < 4; ++mf)
#pragma unroll
            for (int nf = 0; nf < 2; ++nf) acc[mf][nf] = 0.f;
#pragma unroll
        for (int ks = 0; ks < 2; ++ks) {
            bf16x8 a[4], b[2];
#pragma unroll
            for (int mf = 0; mf < 4; ++mf) {
                int ra = mf * 16 + cl;
                a[mf] = *(const bf16x8*)((const char*)As + ra * 128 + swz_off(cl, ks * 4 + rq));
            }
#pragma unroll
            for (int nf = 0; nf < 2; ++nf) {
                int rb = w * 32 + nf * 16 + cl;
                b[nf] = *(const bf16x8*)((const char*)Bs + rb * 128 + swz_off(cl, ks * 4 + rq));
            }
#pragma unroll
            for (int mf = 0; mf < 4; ++mf)
#pragma unroll
                for (int nf = 0; nf < 2; ++nf)
                    acc[mf][nf] = __builtin_amdgcn_mfma_f32_16x16x32_bf16(a[mf], b[nf], acc[mf][nf], 0, 0, 0);
        }
        float mh = mlpmaskf[PN + h];   // uniform
#pragma unroll
        for (int nf = 0; nf < 2; ++nf) {
            int col = n0 + w * 32 + nf * 16 + cl;
            float bv = bO[col] * (1.f / 16.f);
#pragma unroll
            for (int mf = 0; mf < 4; ++mf)
#pragma unroll
                for (int rr = 0; rr < 4; ++rr) {
                    int row = m0 + mf * 16 + rq * 4 + rr;
                    float v = acc[mf][nf][rr] + bv;
                    outp[(size_t)row * (OUTN * DM) + (PN + h) * DM + col] = v;
                    macc[mf][nf][rr] += mh * v;
                }
        }
    }
#pragma unroll
    for (int mf = 0; mf < 4; ++mf)
#pragma unroll
        for (int nf = 0; nf < 2; ++nf) {
            int col = n0 + w * 32 + nf * 16 + cl;
#pragma unroll
            for (int rr = 0; rr < 4; ++rr) {
                int row = m0 + mf * 16 + rq * 4 + rr;
                float v = macc[mf][nf][rr];
                midf[(size_t)row * DM + col] = v;
                midb[(size_t)row * DM + col] = f2bf(v);
            }
        }
}

// ---------------------------------------------------------------------------
extern "C" void kernel_launch(void* const* d_in, const int* in_sizes, int n_in,
                              void* d_out, int out_size, void* d_ws, size_t ws_size,
                              hipStream_t stream) {
    const float* resid = (const float*)d_in[0];
    const float* W_Q = (const float*)d_in[1];
    const float* b_Q = (const float*)d_in[2];
    const float* W_K = (const float*)d_in[3];
    const float* b_K = (const float*)d_in[4];
    const float* W_V = (const float*)d_in[5];
    const float* b_V = (const float*)d_in[6];
    const float* W_O = (const float*)d_in[7];
    const float* b_O = (const float*)d_in[8];
    const float* mql = (const float*)d_in[9];
    const float* mkl = (const float*)d_in[10];
    const float* mvl = (const float*)d_in[11];
    const float* mml = (const float*)d_in[12];
    const float* W_in = (const float*)d_in[13];
    const float* b_in = (const float*)d_in[14];
    const float* W_out = (const float*)d_in[15];
    const float* b_out = (const float*)d_in[16];
    float* out = (float*)d_out;
    (void)in_sizes; (void)n_in; (void)out_size; (void)ws_size;

    char* ws = (char*)d_ws;
    size_t off = 0;
    auto carve = [&](size_t bytes) -> void* {
        void* p = ws + off;
        off += (bytes + 255) & ~(size_t)255;
        return p;
    };
    unsigned short* nrm = (unsigned short*)carve((size_t)48 * SEQ * DM * 2);  // 192 MB
    float* statsQ = (float*)carve((size_t)48 * SEQ * 2 * 4);
    unsigned short* qkv = (unsigned short*)carve((size_t)48 * SEQ * DH * 2);  // q,k slices used
    unsigned short* vtb = (unsigned short*)carve((size_t)NHEADS * DH * SEQ * 2);
    unsigned short* zbuf = (unsigned short*)carve((size_t)NHEADS * SEQ * DH * 2);
    unsigned short* midb = (unsigned short*)carve((size_t)SEQ * DM * 2);
    float* midf = (float*)carve((size_t)SEQ * DM * 4);
    float* statsM = (float*)carve((size_t)SEQ * 2 * 4);
    unsigned short* act = (unsigned short*)carve((size_t)SEQ * DMLP * 2);
    float* rot = (float*)carve((size_t)SEQ * 64 * 4);
    float* colWqkv = (float*)carve((size_t)48 * 64 * 4);
    float* colWin = (float*)carve((size_t)DMLP * 4);
    float* mlpmaskf = (float*)carve((size_t)64 * 4);
    float* biasQKV = (float*)carve((size_t)48 * 64 * 4);
    unsigned long long* maskbits = (unsigned long long*)carve((size_t)64 * 8);
    float* prevpart = (float*)carve((size_t)SEQ * DM * 4);                    // 8 MB
    unsigned short* WtQKV = (unsigned short*)carve((size_t)48 * DH * DM * 2); // 6 MB
    unsigned short* WtO = (unsigned short*)carve((size_t)16 * DM * DH * 2);   // 2 MB
    unsigned short* WtIn = (unsigned short*)carve((size_t)DMLP * DM * 2);     // 8 MB
    unsigned short* WtOut = (unsigned short*)carve((size_t)DM * DMLP * 2);    // 8 MB

    prep_all<<<260, 256, 0, stream>>>(mql, mkl, mvl, mml, b_Q, b_K, b_V,
                                      rot, maskbits, mlpmaskf, biasQKV, colWqkv, colWin);

    wtrans<<<dim3(2, 32, 16), 256, 0, stream>>>(W_Q, WtQKV, DM, DH, (size_t)DM * DH, (size_t)DH * DM, colWqkv, 64);
    wtrans<<<dim3(2, 32, 16), 256, 0, stream>>>(W_K, WtQKV + (size_t)16 * DH * DM, DM, DH, (size_t)DM * DH, (size_t)DH * DM, colWqkv + 1024, 64);
    wtrans<<<dim3(2, 32, 16), 256, 0, stream>>>(W_V, WtQKV + (size_t)32 * DH * DM, DM, DH, (size_t)DM * DH, (size_t)DH * DM, colWqkv + 2048, 64);
    wtrans<<<dim3(32, 2, 16), 256, 0, stream>>>(W_O, WtO, DH, DM, (size_t)DH * DM, (size_t)DM * DH, nullptr, 0);
    wtrans<<<dim3(128, 32, 1), 256, 0, stream>>>(W_in, WtIn, DM, DMLP, 0, 0, colWin, 0);
    wtrans<<<dim3(32, 128, 1), 256, 0, stream>>>(W_out, WtOut, DMLP, DM, 0, 0, nullptr, 0);

    k1_masked_norm<<<SEQ, 512, 0, stream>>>(resid, maskbits, out, nrm, statsQ, prevpart);

    // QKV projection: 48 GEMMs (2048x1024x64); V written transposed to vtb
    gemm2<2, 4, 4, 1, 1><<<dim3(16, 1, 48), 256, 0, stream>>>(
        nrm, (size_t)SEQ * DM, DM,
        WtQKV, (size_t)DH * DM, DM,
        nullptr, qkv, (size_t)SEQ * DH, DH,
        statsQ, SEQ,
        colWqkv, 64,
        biasQKV, 64, 1.f,
        rot, vtb, DM);

    flash_k<<<dim3(16, 16), 256, 0, stream>>>(qkv, vtb, zbuf);

    attn_fused<<<dim3(32, 8), 256, 0, stream>>>(zbuf, WtO, b_O, mlpmaskf, prevpart, out, midb, midf);

    stats_k<<<SEQ, 256, 0, stream>>>(midf, statsM);

    // MLP1: (2048x1024)@(1024x4096), LN fold + b_in + gelu -> act
    gemm2<4, 4, 2, 2, 2><<<dim3(16, 32, 1), 256, 0, stream>>>(
        midb, 0, DM,
        WtIn, 0, DM,
        nullptr, act, 0, DMLP,
        statsM, 0,
        colWin, 0,
        b_in, 0, 1.f,
        nullptr, nullptr, DM);

    // MLP2: (2048x4096)@(4096x1024) + b_out -> d_out row 51
    gemm2<2, 4, 2, 2, 0><<<dim3(32, 8, 1), 256, 0, stream>>>(
        act, 0, DMLP,
        WtOut, 0, DMLP,
        out + 51 * DM, nullptr, 0, OUTN * DM,
        nullptr, 0, nullptr, 0,
        b_out, 0, 1.f,
        nullptr, nullptr, DMLP);
}

// Round 4
// 524.744 us; speedup vs baseline: 2.3929x; 1.1025x over previous
//
#include <hip/hip_runtime.h>
#include <stdint.h>

// ---------------------------------------------------------------------------
// TransformerBlock (masked-subnetwork block) for MI355X / gfx950.  Round 4:
//  - k1 rewritten: branchless mask-FMA (cvt from uniform bit + v_fmac), th
//    processed in groups of 8 (16 independent acc chains), v_cvt_pk_bf16_f32
//    packing, launch_bounds(512,4) so r[35] stays in registers.
//  - rest identical to round 3.
// ---------------------------------------------------------------------------

#define SEQ 2048
#define DM 1024
#define NHEADS 16
#define DH 64
#define DMLP 4096
#define PN 35
#define TOTN 51
#define OUTN 52
#define LNEPS 1e-5f
#define L2E 1.44269504088896340736f

typedef __bf16 bf16x8 __attribute__((ext_vector_type(8)));
typedef float f32x4 __attribute__((ext_vector_type(4)));
typedef unsigned short u16x8 __attribute__((ext_vector_type(8)));

static __device__ __forceinline__ unsigned short f2bf(float f) {
    unsigned int u = __builtin_bit_cast(unsigned int, f);
    u += 0x7fffu + ((u >> 16) & 1u);
    return (unsigned short)(u >> 16);
}

static __device__ __forceinline__ unsigned int cvt_pk_bf16(float lo, float hi) {
    unsigned int pk;
    asm("v_cvt_pk_bf16_f32 %0, %1, %2" : "=v"(pk) : "v"(lo), "v"(hi));
    return pk;
}

static __device__ __forceinline__ float gelu_tanh(float x) {
    float u = 0.7978845608028654f * x * (1.f + 0.044715f * x * x);
    float e = exp2f(u * (2.f * L2E));          // e^{2u}
    float th = 1.f - 2.f / (e + 1.f);          // tanh(u)
    return 0.5f * x * (1.f + th);
}

// async global->LDS, 16B per lane; lds dest wave-uniform base + lane*16.
static __device__ __forceinline__ void gload_lds16(const void* g, void* l) {
    __builtin_amdgcn_global_load_lds(
        (const __attribute__((address_space(1))) unsigned int*)g,
        (__attribute__((address_space(3))) unsigned int*)l, 16, 0, 0);
}

// XOR-granule swizzle: LDS[row][g] holds global[row][g ^ (row&7)], g = 16B
// granule within a 128B row.  Staging source column (in shorts) for a lane:
static __device__ __forceinline__ int swz_src(int lane) {
    return ((lane & 7) ^ ((lane >> 3) & 7)) * 8;
}
// read-side byte offset within the row for logical granule g of row r:
static __device__ __forceinline__ int swz_off(int r, int g) {
    return ((g ^ (r & 7)) * 16);
}

// ---------------------------------------------------------------------------
// prep: rotary table, mask bitmaps, biases, zero colsum buffers.  grid 260.
// ---------------------------------------------------------------------------
__global__ void prep_all(const float* __restrict__ mq, const float* __restrict__ mk,
                         const float* __restrict__ mv, const float* __restrict__ mmlp,
                         const float* __restrict__ bQ, const float* __restrict__ bK,
                         const float* __restrict__ bV,
                         float* __restrict__ rot, unsigned long long* __restrict__ maskbits,
                         float* __restrict__ mlpmaskf, float* __restrict__ biasQKV,
                         float* __restrict__ colWqkv, float* __restrict__ colWin) {
    int bid = blockIdx.x, tid = threadIdx.x;
    if (bid < 256) {
        int id = bid * 256 + tid;            // 2048*32
        int s = id >> 5, j = id & 31;
        float freq = powf(10000.f, (float)j * (1.f / 32.f));
        float ang = (float)s / freq;
        rot[s * 64 + j] = sinf(ang);
        rot[s * 64 + 32 + j] = cosf(ang);
    } else if (bid == 256) {
        if (tid < 48) {
            int ty = tid >> 4, h = tid & 15;
            const float* src = (ty == 0) ? mq : (ty == 1 ? mk : mv);
            unsigned long long bits = 0;
            for (int n = 0; n < PN; ++n)
                if (src[n * NHEADS + h] > 0.f) bits |= 1ull << n;
            maskbits[tid] = bits;
            const float* bsrc = (ty == 0) ? bQ : (ty == 1 ? bK : bV);
            for (int d = 0; d < DH; ++d) biasQKV[tid * 64 + d] = bsrc[h * DH + d];
        }
        if (tid == 48) {
            unsigned long long bits = 0;
            for (int n = 0; n < PN; ++n)
                if (mmlp[n] > 0.f) bits |= 1ull << n;
            maskbits[48] = bits;
        }
        if (tid < 64) mlpmaskf[tid] = (tid < TOTN && mmlp[tid] > 0.f) ? 1.f : 0.f;
    } else if (bid == 257) {
        for (int i = tid; i < 3072; i += 256) colWqkv[i] = 0.f;
    } else {
        int base = (bid - 258) * 2048;
        for (int i = tid; i < 2048; i += 256) colWin[base + i] = 0.f;
    }
}

// ---------------------------------------------------------------------------
// transpose+convert: in f32 KxN row-major -> out bf16 NxK row-major (per z);
// optionally accumulates column sums (over K) into colsum[z*colZ + n].
// ---------------------------------------------------------------------------
__global__ void wtrans(const float* __restrict__ in, unsigned short* __restrict__ out,
                       int K, int N, size_t inZ, size_t outZ,
                       float* __restrict__ colsum, size_t colZ) {
    int z = blockIdx.z;
    const float* ib = in + (size_t)z * inZ;
    unsigned short* ob = out + (size_t)z * outZ;
    __shared__ float t[32][33];
    int n0 = blockIdx.x * 32, k0 = blockIdx.y * 32;
    int tx = threadIdx.x & 31, ty = threadIdx.x >> 5;   // 32x8
#pragma unroll
    for (int r = 0; r < 4; ++r) {
        int k = ty + r * 8;
        t[k][tx] = ib[(size_t)(k0 + k) * N + n0 + tx];
    }
    __syncthreads();
#pragma unroll
    for (int r = 0; r < 4; ++r) {
        int n = ty + r * 8;
        ob[(size_t)(n0 + n) * K + k0 + tx] = f2bf(t[tx][n]);
    }
    if (colsum != nullptr && ty == 0) {
        float s = 0.f;
#pragma unroll
        for (int k = 0; k < 32; ++k) s += t[k][tx];
        atomicAdd(&colsum[(size_t)z * colZ + n0 + tx], s);
    }
}

// ---------------------------------------------------------------------------
// K1: per position s: copy resid_pre -> out rows 0..34, 48 masked sums (bf16)
// + LN stats, and the masked-prev-node MLP partial (f32).
// Branchless: mask bit -> float via v_cvt (uniform SGPR src), v_fmac chains
// interleaved 8 ths at a time.
// ---------------------------------------------------------------------------
__launch_bounds__(512, 4)
__global__ void k1_masked_norm(const float* __restrict__ resid,
                               const unsigned long long* __restrict__ maskbits,
                               float* __restrict__ outp,
                               unsigned short* __restrict__ nrm,
                               float* __restrict__ stats,
                               float* __restrict__ prevpart) {
    int s = blockIdx.x;
    int tid = threadIdx.x;
    int lane = tid & 63, w = tid >> 6;
    const float2* rp = (const float2*)(resid + (size_t)s * PN * DM);
    float2* outv = (float2*)(outp + (size_t)s * OUTN * DM);
    float2 r[PN];
#pragma unroll
    for (int n = 0; n < PN; ++n) {
        float2 v = rp[n * (DM / 2) + tid];
        r[n] = v;
        outv[n * (DM / 2) + tid] = v;
    }
    __shared__ float wpart[8][48][2];
#pragma unroll 1
    for (int g = 0; g < 6; ++g) {
        unsigned long long b[8];
#pragma unroll
        for (int t = 0; t < 8; ++t) b[t] = maskbits[g * 8 + t];   // uniform s_loads
        float sx[8], sy[8];
#pragma unroll
        for (int t = 0; t < 8; ++t) { sx[t] = 0.f; sy[t] = 0.f; }
#pragma unroll
        for (int n = 0; n < PN; ++n) {
#pragma unroll
            for (int t = 0; t < 8; ++t) {
                float f = (float)((unsigned int)(b[t] >> n) & 1u);  // s_lshr+s_and+v_cvt
                sx[t] += f * r[n].x;
                sy[t] += f * r[n].y;
            }
        }
#pragma unroll
        for (int t = 0; t < 8; ++t) {
            int th = g * 8 + t;
            ((unsigned int*)nrm)[((size_t)th * SEQ + s) * (DM / 2) + tid] =
                cvt_pk_bf16(sx[t], sy[t]);
            float p1 = sx[t] + sy[t];
            float p2 = sx[t] * sx[t] + sy[t] * sy[t];
#pragma unroll
            for (int d = 1; d < 64; d <<= 1) {
                p1 += __shfl_xor(p1, d);
                p2 += __shfl_xor(p2, d);
            }
            if (lane == 0) { wpart[w][th][0] = p1; wpart[w][th][1] = p2; }
        }
    }
    {
        unsigned long long bm = maskbits[48];
        float px = 0.f, py = 0.f;
#pragma unroll
        for (int n = 0; n < PN; ++n) {
            float f = (float)((unsigned int)(bm >> n) & 1u);
            px += f * r[n].x;
            py += f * r[n].y;
        }
        ((float2*)prevpart)[(size_t)s * (DM / 2) + tid] = make_float2(px, py);
    }
    __syncthreads();
    if (tid < 48) {
        float S1 = 0.f, S2 = 0.f;
        for (int ww = 0; ww < 8; ++ww) { S1 += wpart[ww][tid][0]; S2 += wpart[ww][tid][1]; }
        float mean = S1 * (1.f / DM);
        float var = S2 * (1.f / DM) - mean * mean;
        float* st = stats + ((size_t)tid * SEQ + s) * 2;
        st[0] = mean;
        st[1] = rsqrtf(var + LNEPS);
    }
}

// ---------------------------------------------------------------------------
// stats of mid rows (f32, 2048x1024) -> statsM
// ---------------------------------------------------------------------------
__launch_bounds__(256, 4)
__global__ void stats_k(const float* __restrict__ midf, float* __restrict__ stats) {
    int s = blockIdx.x, tid = threadIdx.x;
    int lane = tid & 63, w = tid >> 6;
    float4 v = ((const float4*)midf)[(size_t)s * (DM / 4) + tid];
    float p1 = v.x + v.y + v.z + v.w;
    float p2 = v.x * v.x + v.y * v.y + v.z * v.z + v.w * v.w;
#pragma unroll
    for (int d = 1; d < 64; d <<= 1) { p1 += __shfl_xor(p1, d); p2 += __shfl_xor(p2, d); }
    __shared__ float wp[4][2];
    if (lane == 0) { wp[w][0] = p1; wp[w][1] = p2; }
    __syncthreads();
    if (tid == 0) {
        float S1 = wp[0][0] + wp[1][0] + wp[2][0] + wp[3][0];
        float S2 = wp[0][1] + wp[1][1] + wp[2][1] + wp[3][1];
        float mean = S1 * (1.f / DM);
        float var = S2 * (1.f / DM) - mean * mean;
        stats[s * 2] = mean;
        stats[s * 2 + 1] = rsqrtf(var + LNEPS);
    }
}

// ---------------------------------------------------------------------------
// m97-style bf16 GEMM: A MxK bf16 row-major, Bt NxK bf16 row-major.
// C = A*Bt^T.  gload_lds(16B) staging, XOR-granule swizzled LDS, BK=64.
// EPI 0: f32 out + bias*scale
// EPI 1: LN-affine + bias + rotary(q,k) + q*0.125 -> bf16; V written
//        transposed [h][d][s] to Vt.
// EPI 2: LN-affine + bias + gelu -> bf16
// ---------------------------------------------------------------------------
template <int MF, int NF, int WGM, int WGN, int EPI>
__launch_bounds__(256, 2)
__global__ void gemm2(const unsigned short* __restrict__ A, size_t aZ, int lda,
                      const unsigned short* __restrict__ Bt, size_t bZ, int ldb,
                      float* __restrict__ Cf, unsigned short* __restrict__ Cb,
                      size_t cZ, int ldc,
                      const float* __restrict__ stats, size_t statsZ,
                      const float* __restrict__ colW, size_t colwZ,
                      const float* __restrict__ bias, size_t biasZ, float biasScale,
                      const float* __restrict__ rot, unsigned short* __restrict__ Vt,
                      int K) {
    constexpr int BM = WGM * 16 * MF;
    constexpr int BN = WGN * 16 * NF;
    constexpr int nA = BM / 32;
    constexpr int nB = BN / 32;
    __shared__ unsigned short As[BM * 64];   // linear 128B rows, swizzled granules
    __shared__ unsigned short Bs[BN * 64];
    const int tid = threadIdx.x;
    const int lane = tid & 63;
    const int w = tid >> 6;
    const int wm = w % WGM, wn = w / WGM;
    const int z = blockIdx.z;
    const int m0 = blockIdx.x * BM;
    const int n0 = blockIdx.y * BN;
    const int cl = lane & 15, rq = lane >> 4;

    const unsigned short* Ab = A + (size_t)z * aZ + (size_t)m0 * lda;
    const unsigned short* Bb = Bt + (size_t)z * bZ + (size_t)n0 * ldb;
    const int lrow8 = lane >> 3;
    const int scol = swz_src(lane);

    f32x4 acc[MF][NF];
#pragma unroll
    for (int mf = 0; mf < MF; ++mf)
#pragma unroll
        for (int nf = 0; nf < NF; ++nf) acc[mf][nf] = 0.f;

    for (int k0 = 0; k0 < K; k0 += 64) {
        __syncthreads();
#pragma unroll
        for (int i = 0; i < nA; ++i) {
            int c = w * nA + i;
            int row = c * 8 + lrow8;
            gload_lds16(Ab + (size_t)row * lda + k0 + scol, (char*)As + c * 1024);
        }
#pragma unroll
        for (int i = 0; i < nB; ++i) {
            int c = w * nB + i;
            int row = c * 8 + lrow8;
            gload_lds16(Bb + (size_t)row * ldb + k0 + scol, (char*)Bs + c * 1024);
        }
        __syncthreads();
#pragma unroll
        for (int ks = 0; ks < 2; ++ks) {
            bf16x8 a[MF], b[NF];
#pragma unroll
            for (int mf = 0; mf < MF; ++mf) {
                int ra = (wm * MF + mf) * 16 + cl;
                a[mf] = *(const bf16x8*)((const char*)As + ra * 128 + swz_off(cl, ks * 4 + rq));
            }
#pragma unroll
            for (int nf = 0; nf < NF; ++nf) {
                int rb = (wn * NF + nf) * 16 + cl;
                b[nf] = *(const bf16x8*)((const char*)Bs + rb * 128 + swz_off(cl, ks * 4 + rq));
            }
#pragma unroll
            for (int mf = 0; mf < MF; ++mf)
#pragma unroll
                for (int nf = 0; nf < NF; ++nf)
                    acc[mf][nf] = __builtin_amdgcn_mfma_f32_16x16x32_bf16(a[mf], b[nf], acc[mf][nf], 0, 0, 0);
        }
    }

    if constexpr (EPI == 0) {
        float* Cz = Cf + (size_t)z * cZ;
        const float* bz = bias + (size_t)z * biasZ;
#pragma unroll
        for (int mf = 0; mf < MF; ++mf)
#pragma unroll
            for (int nf = 0; nf < NF; ++nf) {
                int col = n0 + wn * (16 * NF) + nf * 16 + cl;
                float bv = bz[col] * biasScale;
#pragma unroll
                for (int rr = 0; rr < 4; ++rr) {
                    int row = m0 + wm * (16 * MF) + mf * 16 + rq * 4 + rr;
                    Cz[(size_t)row * ldc + col] = acc[mf][nf][rr] + bv;
                }
            }
    } else if constexpr (EPI == 1) {
        const int t = z >> 4;                      // 0=q 1=k 2=v
        const int h = z & 15;
        const float qs = (t == 0) ? 0.125f : 1.f;
        float vals[MF][NF][4];
        float meanv[MF][4], invv[MF][4];
#pragma unroll
        for (int mf = 0; mf < MF; ++mf)
#pragma unroll
            for (int rr = 0; rr < 4; ++rr) {
                int row = m0 + wm * (16 * MF) + mf * 16 + rq * 4 + rr;
                const float* st = stats + ((size_t)z * statsZ + row) * 2;
                meanv[mf][rr] = st[0];
                invv[mf][rr] = st[1];
            }
#pragma unroll
        for (int nf = 0; nf < NF; ++nf) {
            int col = n0 + wn * (16 * NF) + nf * 16 + cl;
            float cw = colW[(size_t)z * colwZ + col];
            float bv = bias[(size_t)z * biasZ + col];
#pragma unroll
            for (int mf = 0; mf < MF; ++mf)
#pragma unroll
                for (int rr = 0; rr < 4; ++rr)
                    vals[mf][nf][rr] = (acc[mf][nf][rr] - meanv[mf][rr] * cw) * invv[mf][rr] + bv;
        }
        if (t < 2) {   // rotary on q,k  (WGN==1, n0==0, NF==4 -> pairs (nf, nf+2))
#pragma unroll
            for (int nf = 0; nf < NF / 2; ++nf) {
                int j = nf * 16 + cl;
#pragma unroll
                for (int mf = 0; mf < MF; ++mf)
#pragma unroll
                    for (int rr = 0; rr < 4; ++rr) {
                        int row = m0 + wm * (16 * MF) + mf * 16 + rq * 4 + rr;
                        float sn = rot[row * 64 + j];
                        float cs = rot[row * 64 + 32 + j];
                        float lo = vals[mf][nf][rr], hi = vals[mf][nf + 2][rr];
                        vals[mf][nf][rr] = lo * cs - hi * sn;
                        vals[mf][nf + 2][rr] = hi * cs + lo * sn;
                    }
            }
        }
        if (t == 2) {
            // V: write transposed [h][d][s], 4 consecutive s packed per store
#pragma unroll
            for (int mf = 0; mf < MF; ++mf)
#pragma unroll
                for (int nf = 0; nf < NF; ++nf) {
                    int col = nf * 16 + cl;   // d
                    int row0 = m0 + wm * (16 * MF) + mf * 16 + rq * 4;
                    ushort4 pk;
                    pk.x = f2bf(vals[mf][nf][0]);
                    pk.y = f2bf(vals[mf][nf][1]);
                    pk.z = f2bf(vals[mf][nf][2]);
                    pk.w = f2bf(vals[mf][nf][3]);
                    *(ushort4*)&Vt[((size_t)h * DH + col) * SEQ + row0] = pk;
                }
        } else {
            unsigned short* Cz = Cb + (size_t)z * cZ;
#pragma unroll
            for (int mf = 0; mf < MF; ++mf)
#pragma unroll
                for (int nf = 0; nf < NF; ++nf) {
                    int col = n0 + wn * (16 * NF) + nf * 16 + cl;
#pragma unroll
                    for (int rr = 0; rr < 4; ++rr) {
                        int row = m0 + wm * (16 * MF) + mf * 16 + rq * 4 + rr;
                        Cz[(size_t)row * ldc + col] = f2bf(vals[mf][nf][rr] * qs);
                    }
                }
        }
    } else {  // EPI == 2 : LN-affine + bias + gelu -> bf16
        unsigned short* Cz = Cb;
#pragma unroll
        for (int mf = 0; mf < MF; ++mf)
#pragma unroll
            for (int rr = 0; rr < 4; ++rr) {
                int row = m0 + wm * (16 * MF) + mf * 16 + rq * 4 + rr;
                const float* st = stats + (size_t)row * 2;
                float mean = st[0], inv = st[1];
#pragma unroll
                for (int nf = 0; nf < NF; ++nf) {
                    int col = n0 + wn * (16 * NF) + nf * 16 + cl;
                    float x = (acc[mf][nf][rr] - mean * colW[col]) * inv + bias[col];
                    Cz[(size_t)row * ldc + col] = f2bf(gelu_tanh(x));
                }
            }
    }
}

// ---------------------------------------------------------------------------
// Flash attention: balanced pairs {p, 31-p} of 64-row q-tiles, 16 heads.
// K staged [k][d], V^T staged [d][k], both via gload_lds with swizzle.
// ---------------------------------------------------------------------------
__launch_bounds__(256, 2)
__global__ void flash_k(const unsigned short* __restrict__ qkv,
                        const unsigned short* __restrict__ vt,
                        unsigned short* __restrict__ zbuf) {
    const int p = blockIdx.x, h = blockIdx.y;
    const int tid = threadIdx.x, lane = tid & 63, w = tid >> 6;
    const int cl = lane & 15, rq = lane >> 4;
    const int lrow8 = lane >> 3;
    const int scol = swz_src(lane);
    const unsigned short* qb = qkv + ((size_t)h * SEQ) * DH;
    const unsigned short* kb = qkv + ((size_t)(16 + h) * SEQ) * DH;
    const unsigned short* vtb = vt + (size_t)h * DH * SEQ;

    __shared__ unsigned short Ks[64 * 64];   // [k][d] swizzled
    __shared__ unsigned short Vs[64 * 64];   // [d][k] swizzled
    __shared__ unsigned short Ps[64][72];    // padded, scalar writes

#pragma unroll 1
    for (int half = 0; half < 2; ++half) {
        const int qi = half ? (31 - p) : p;
        const int q0 = qi * 64;

        bf16x8 aq[2];
        {
            int qrow = q0 + w * 16 + cl;
            const unsigned short* qp = qb + (size_t)qrow * DH + rq * 8;
            aq[0] = *(const bf16x8*)(qp);
            aq[1] = *(const bf16x8*)(qp + 32);
        }
        float m_run[4] = {-3e38f, -3e38f, -3e38f, -3e38f};
        float l_run[4] = {0.f, 0.f, 0.f, 0.f};
        f32x4 accz[4];
#pragma unroll
        for (int nf = 0; nf < 4; ++nf) accz[nf] = 0.f;

#pragma unroll 1
        for (int j = 0; j <= qi; ++j) {
            __syncthreads();
#pragma unroll
            for (int i = 0; i < 2; ++i) {
                int c = w * 2 + i;
                int row = c * 8 + lrow8;
                gload_lds16(kb + (size_t)(j * 64 + row) * DH + scol, (char*)Ks + c * 1024);
                gload_lds16(vtb + (size_t)row * SEQ + j * 64 + scol, (char*)Vs + c * 1024);
            }
            __syncthreads();

            f32x4 sfr[4];
#pragma unroll
            for (int nf = 0; nf < 4; ++nf) sfr[nf] = 0.f;
#pragma unroll
            for (int df = 0; df < 2; ++df)
#pragma unroll
                for (int nf = 0; nf < 4; ++nf) {
                    int rb = nf * 16 + cl;
                    bf16x8 b = *(const bf16x8*)((const char*)Ks + rb * 128 + swz_off(cl, df * 4 + rq));
                    sfr[nf] = __builtin_amdgcn_mfma_f32_16x16x32_bf16(aq[df], b, sfr[nf], 0, 0, 0);
                }
            if (j == qi) {
#pragma unroll
                for (int nf = 0; nf < 4; ++nf)
#pragma unroll
                    for (int rr = 0; rr < 4; ++rr) {
                        int qg = q0 + w * 16 + rq * 4 + rr;
                        int kg = j * 64 + nf * 16 + cl;
                        if (kg > qg) sfr[nf][rr] = -1e5f;
                    }
            }
            float mnew[4], corr[4], psum[4];
#pragma unroll
            for (int rr = 0; rr < 4; ++rr) {
                float t0 = fmaxf(fmaxf(sfr[0][rr], sfr[1][rr]), fmaxf(sfr[2][rr], sfr[3][rr]));
                t0 = fmaxf(t0, __shfl_xor(t0, 1));
                t0 = fmaxf(t0, __shfl_xor(t0, 2));
                t0 = fmaxf(t0, __shfl_xor(t0, 4));
                t0 = fmaxf(t0, __shfl_xor(t0, 8));
                mnew[rr] = fmaxf(m_run[rr], t0);
                corr[rr] = exp2f((m_run[rr] - mnew[rr]) * L2E);
                psum[rr] = 0.f;
            }
#pragma unroll
            for (int nf = 0; nf < 4; ++nf)
#pragma unroll
                for (int rr = 0; rr < 4; ++rr) {
                    float pv = exp2f((sfr[nf][rr] - mnew[rr]) * L2E);
                    sfr[nf][rr] = pv;
                    psum[rr] += pv;
                }
#pragma unroll
            for (int rr = 0; rr < 4; ++rr) {
                float ps = psum[rr];
                ps += __shfl_xor(ps, 1);
                ps += __shfl_xor(ps, 2);
                ps += __shfl_xor(ps, 4);
                ps += __shfl_xor(ps, 8);
                l_run[rr] = l_run[rr] * corr[rr] + ps;
                m_run[rr] = mnew[rr];
            }
#pragma unroll
            for (int nf = 0; nf < 4; ++nf)
#pragma unroll
                for (int rr = 0; rr < 4; ++rr) accz[nf][rr] *= corr[rr];

#pragma unroll
            for (int nf = 0; nf < 4; ++nf)
#pragma unroll
                for (int rr = 0; rr < 4; ++rr)
                    Ps[w * 16 + rq * 4 + rr][nf * 16 + cl] = f2bf(sfr[nf][rr]);
#pragma unroll
            for (int ks = 0; ks < 2; ++ks) {
                bf16x8 ap = *(const bf16x8*)&Ps[w * 16 + cl][ks * 32 + rq * 8];
#pragma unroll
                for (int nf = 0; nf < 4; ++nf) {
                    int rb = nf * 16 + cl;
                    bf16x8 bv = *(const bf16x8*)((const char*)Vs + rb * 128 + swz_off(cl, ks * 4 + rq));
                    accz[nf] = __builtin_amdgcn_mfma_f32_16x16x32_bf16(ap, bv, accz[nf], 0, 0, 0);
                }
            }
        }
#pragma unroll
        for (int nf = 0; nf < 4; ++nf)
#pragma unroll
            for (int rr = 0; rr < 4; ++rr) {
                int qg = q0 + w * 16 + rq * 4 + rr;
                zbuf[((size_t)h * SEQ + qg) * DH + nf * 16 + cl] = f2bf(accz[nf][rr] / l_run[rr]);
            }
        __syncthreads();   // protect LDS before next half re-stages
    }
}

// ---------------------------------------------------------------------------
// Fused attn-out: per block (64 s-rows x 128 model cols), loop 16 heads:
// GEMM z_h @ W_O_h + b_O/16 -> out row 35+h, accumulate masked MLP residual,
// add prevpart, write mid (bf16 + f32).
// ---------------------------------------------------------------------------
__launch_bounds__(256, 2)
__global__ void attn_fused(const unsigned short* __restrict__ zbuf,
                           const unsigned short* __restrict__ WtO,
                           const float* __restrict__ bO,
                           const float* __restrict__ mlpmaskf,
                           const float* __restrict__ prevpart,
                           float* __restrict__ outp,
                           unsigned short* __restrict__ midb,
                           float* __restrict__ midf) {
    __shared__ unsigned short As[64 * 64];    // z tile [s][d]
    __shared__ unsigned short Bs[128 * 64];   // W_O^T tile [m][d]
    const int tid = threadIdx.x;
    const int lane = tid & 63;
    const int w = tid >> 6;          // WGM=1, WGN=4 -> wn = w
    const int cl = lane & 15, rq = lane >> 4;
    const int lrow8 = lane >> 3;
    const int scol = swz_src(lane);
    const int m0 = blockIdx.x * 64;
    const int n0 = blockIdx.y * 128;

    f32x4 macc[4][2];
#pragma unroll
    for (int mf = 0; mf < 4; ++mf)
#pragma unroll
        for (int nf = 0; nf < 2; ++nf)
#pragma unroll
            for (int rr = 0; rr < 4; ++rr) {
                int row = m0 + mf * 16 + rq * 4 + rr;
                int col = n0 + w * 32 + nf * 16 + cl;
                macc[mf][nf][rr] = prevpart[(size_t)row * DM + col];
            }

#pragma unroll 1
    for (int h = 0; h < NHEADS; ++h) {
        __syncthreads();
#pragma unroll
        for (int i = 0; i < 2; ++i) {
            int c = w * 2 + i;
            int row = c * 8 + lrow8;
            gload_lds16(zbuf + ((size_t)h * SEQ + m0 + row) * DH + scol, (char*)As + c * 1024);
        }
#pragma unroll
        for (int i = 0; i < 4; ++i) {
            int c = w * 4 + i;
            int row = c * 8 + lrow8;
            gload_lds16(WtO + ((size_t)h * DM + n0 + row) * DH + scol, (char*)Bs + c * 1024);
        }
        __syncthreads();
        f32x4 acc[4][2];
#pragma unroll
        for (int mf = 0; mf < 4; ++mf)
#pragma unroll
            for (int nf = 0; nf < 2; ++nf) acc[mf][nf] = 0.f;
#pragma unroll
        for (int ks = 0; ks < 2; ++ks) {
            bf16x8 a[4], b[2];
#pragma unroll
            for (int mf = 0; mf < 4; ++mf) {
                int ra = mf * 16 + cl;
                a[mf] = *(const bf16x8*)((const char*)As + ra * 128 + swz_off(cl, ks * 4 + rq));
            }
#pragma unroll
            for (int nf = 0; nf < 2; ++nf) {
                int rb = w * 32 + nf * 16 + cl;
                b[nf] = *(const bf16x8*)((const char*)Bs + rb * 128 + swz_off(cl, ks * 4 + rq));
            }
#pragma unroll
            for (int mf = 0; mf < 4; ++mf)
#pragma unroll
                for (int nf = 0; nf < 2; ++nf)
                    acc[mf][nf] = __builtin_amdgcn_mfma_f32_16x16x32_bf16(a[mf], b[nf], acc[mf][nf], 0, 0, 0);
        }
        float mh = mlpmaskf[PN + h];   // uniform
#pragma unroll
        for (int nf = 0; nf < 2; ++nf) {
            int col = n0 + w * 32 + nf * 16 + cl;
            float bv = bO[col] * (1.f / 16.f);
#pragma unroll
            for (int mf = 0; mf < 4; ++mf)
#pragma unroll
                for (int rr = 0; rr < 4; ++rr) {
                    int row = m0 + mf * 16 + rq * 4 + rr;
                    float v = acc[mf][nf][rr] + bv;
                    outp[(size_t)row * (OUTN * DM) + (PN + h) * DM + col] = v;
                    macc[mf][nf][rr] += mh * v;
                }
        }
    }
#pragma unroll
    for (int mf = 0; mf < 4; ++mf)
#pragma unroll
        for (int nf = 0; nf < 2; ++nf) {
            int col = n0 + w * 32 + nf * 16 + cl;
#pragma unroll
            for (int rr = 0; rr < 4; ++rr) {
                int row = m0 + mf * 16 + rq * 4 + rr;
                float v = macc[mf][nf][rr];
                midf[(size_t)row * DM + col] = v;
                midb[(size_t)row * DM + col] = f2bf(v);
            }
        }
}

// ---------------------------------------------------------------------------
extern "C" void kernel_launch(void* const* d_in, const int* in_sizes, int n_in,
                              void* d_out, int out_size, void* d_ws, size_t ws_size,
                              hipStream_t stream) {
    const float* resid = (const float*)d_in[0];
    const float* W_Q = (const float*)d_in[1];
    const float* b_Q = (const float*)d_in[2];
    const float* W_K = (const float*)d_in[3];
    const float* b_K = (const float*)d_in[4];
    const float* W_V = (const float*)d_in[5];
    const float* b_V = (const float*)d_in[6];
    const float* W_O = (const float*)d_in[7];
    const float* b_O = (const float*)d_in[8];
    const float* mql = (const float*)d_in[9];
    const float* mkl = (const float*)d_in[10];
    const float* mvl = (const float*)d_in[11];
    const float* mml = (const float*)d_in[12];
    const float* W_in = (const float*)d_in[13];
    const float* b_in = (const float*)d_in[14];
    const float* W_out = (const float*)d_in[15];
    const float* b_out = (const float*)d_in[16];
    float* out = (float*)d_out;
    (void)in_sizes; (void)n_in; (void)out_size; (void)ws_size;

    char* ws = (char*)d_ws;
    size_t off = 0;
    auto carve = [&](size_t bytes) -> void* {
        void* p = ws + off;
        off += (bytes + 255) & ~(size_t)255;
        return p;
    };
    unsigned short* nrm = (unsigned short*)carve((size_t)48 * SEQ * DM * 2);  // 192 MB
    float* statsQ = (float*)carve((size_t)48 * SEQ * 2 * 4);
    unsigned short* qkv = (unsigned short*)carve((size_t)48 * SEQ * DH * 2);  // q,k slices used
    unsigned short* vtb = (unsigned short*)carve((size_t)NHEADS * DH * SEQ * 2);
    unsigned short* zbuf = (unsigned short*)carve((size_t)NHEADS * SEQ * DH * 2);
    unsigned short* midb = (unsigned short*)carve((size_t)SEQ * DM * 2);
    float* midf = (float*)carve((size_t)SEQ * DM * 4);
    float* statsM = (float*)carve((size_t)SEQ * 2 * 4);
    unsigned short* act = (unsigned short*)carve((size_t)SEQ * DMLP * 2);
    float* rot = (float*)carve((size_t)SEQ * 64 * 4);
    float* colWqkv = (float*)carve((size_t)48 * 64 * 4);
    float* colWin = (float*)carve((size_t)DMLP * 4);
    float* mlpmaskf = (float*)carve((size_t)64 * 4);
    float* biasQKV = (float*)carve((size_t)48 * 64 * 4);
    unsigned long long* maskbits = (unsigned long long*)carve((size_t)64 * 8);
    float* prevpart = (float*)carve((size_t)SEQ * DM * 4);                    // 8 MB
    unsigned short* WtQKV = (unsigned short*)carve((size_t)48 * DH * DM * 2); // 6 MB
    unsigned short* WtO = (unsigned short*)carve((size_t)16 * DM * DH * 2);   // 2 MB
    unsigned short* WtIn = (unsigned short*)carve((size_t)DMLP * DM * 2);     // 8 MB
    unsigned short* WtOut = (unsigned short*)carve((size_t)DM * DMLP * 2);    // 8 MB

    prep_all<<<260, 256, 0, stream>>>(mql, mkl, mvl, mml, b_Q, b_K, b_V,
                                      rot, maskbits, mlpmaskf, biasQKV, colWqkv, colWin);

    wtrans<<<dim3(2, 32, 16), 256, 0, stream>>>(W_Q, WtQKV, DM, DH, (size_t)DM * DH, (size_t)DH * DM, colWqkv, 64);
    wtrans<<<dim3(2, 32, 16), 256, 0, stream>>>(W_K, WtQKV + (size_t)16 * DH * DM, DM, DH, (size_t)DM * DH, (size_t)DH * DM, colWqkv + 1024, 64);
    wtrans<<<dim3(2, 32, 16), 256, 0, stream>>>(W_V, WtQKV + (size_t)32 * DH * DM, DM, DH, (size_t)DM * DH, (size_t)DH * DM, colWqkv + 2048, 64);
    wtrans<<<dim3(32, 2, 16), 256, 0, stream>>>(W_O, WtO, DH, DM, (size_t)DH * DM, (size_t)DM * DH, nullptr, 0);
    wtrans<<<dim3(128, 32, 1), 256, 0, stream>>>(W_in, WtIn, DM, DMLP, 0, 0, colWin, 0);
    wtrans<<<dim3(32, 128, 1), 256, 0, stream>>>(W_out, WtOut, DMLP, DM, 0, 0, nullptr, 0);

    k1_masked_norm<<<SEQ, 512, 0, stream>>>(resid, maskbits, out, nrm, statsQ, prevpart);

    // QKV projection: 48 GEMMs (2048x1024x64); V written transposed to vtb
    gemm2<2, 4, 4, 1, 1><<<dim3(16, 1, 48), 256, 0, stream>>>(
        nrm, (size_t)SEQ * DM, DM,
        WtQKV, (size_t)DH * DM, DM,
        nullptr, qkv, (size_t)SEQ * DH, DH,
        statsQ, SEQ,
        colWqkv, 64,
        biasQKV, 64, 1.f,
        rot, vtb, DM);

    flash_k<<<dim3(16, 16), 256, 0, stream>>>(qkv, vtb, zbuf);

    attn_fused<<<dim3(32, 8), 256, 0, stream>>>(zbuf, WtO, b_O, mlpmaskf, prevpart, out, midb, midf);

    stats_k<<<SEQ, 256, 0, stream>>>(midf, statsM);

    // MLP1: (2048x1024)@(1024x4096), LN fold + b_in + gelu -> act
    gemm2<4, 4, 2, 2, 2><<<dim3(16, 32, 1), 256, 0, stream>>>(
        midb, 0, DM,
        WtIn, 0, DM,
        nullptr, act, 0, DMLP,
        statsM, 0,
        colWin, 0,
        b_in, 0, 1.f,
        nullptr, nullptr, DM);

    // MLP2: (2048x4096)@(4096x1024) + b_out -> d_out row 51
    gemm2<2, 4, 2, 2, 0><<<dim3(32, 8, 1), 256, 0, stream>>>(
        act, 0, DMLP,
        WtOut, 0, DMLP,
        out + 51 * DM, nullptr, 0, OUTN * DM,
        nullptr, 0, nullptr, 0,
        b_out, 0, 1.f,
        nullptr, nullptr, DMLP);
}